// Round 1
// baseline (989.768 us; speedup 1.0000x reference)
//
#include <hip/hip_runtime.h>
#include <hip/hip_bf16.h>

typedef unsigned short u16;
typedef unsigned int u32;

#define T_   64
#define D_   300
#define H_   256
#define G_   768            // 3H
#define NROW 512            // useful sequences (s==2)
#define M_   (NROW * T_)    // 32768

__device__ __forceinline__ float bf2f(u16 v) {
    union { u32 u; float f; } x; x.u = ((u32)v) << 16; return x.f;
}
__device__ __forceinline__ u16 f2bf(float f) {
    union { u32 u; float f; } x; x.f = f;
    u32 u = x.u;
    u32 r = (u + 0x7FFFu + ((u >> 16) & 1u)) >> 16;   // RNE
    return (u16)r;
}
__device__ __forceinline__ float sigm(float x) { return 1.f / (1.f + expf(-x)); }

__device__ __forceinline__ float ldx(const float* p, size_t i) { return p[i]; }
__device__ __forceinline__ float ldx(const u16* p, size_t i) { return bf2f(p[i]); }

__device__ __forceinline__ void store8(float* p, const float* v) {
    *reinterpret_cast<float4*>(p)     = make_float4(v[0], v[1], v[2], v[3]);
    *reinterpret_cast<float4*>(p + 4) = make_float4(v[4], v[5], v[6], v[7]);
}
__device__ __forceinline__ void store8(u16* p, const float* v) {
    union { u16 h[8]; uint4 q; } u;
#pragma unroll
    for (int j = 0; j < 8; ++j) u.h[j] = f2bf(v[j]);
    *reinterpret_cast<uint4*>(p) = u.q;
}

// ---------------------------------------------------------------------------
// K0: transpose + cast weights to bf16.
//  y=0: w_hh1  (768x256) -> wt_hh [256][768]
//  y=1: w_ih2f (768x256) -> w2ft  [256][768]
//  y=2: w_ih2b (768x256) -> w2bt  [256][768]
//  y=3: wc1    (256x512) -> wc1t  [512][256]
// ---------------------------------------------------------------------------
__global__ __launch_bounds__(256) void k0_prep(
    const float* __restrict__ w_hh1, const float* __restrict__ w2f,
    const float* __restrict__ w2b, const float* __restrict__ wc1,
    u16* __restrict__ wt_hh, u16* __restrict__ w2ft,
    u16* __restrict__ w2bt, u16* __restrict__ wc1t)
{
    int y = blockIdx.y;
    int tid = blockIdx.x * 256 + threadIdx.x;
    if (y < 3) {
        if (tid < G_ * H_) {
            int k = tid / G_;
            int g = tid % G_;
            const float* src = (y == 0) ? w_hh1 : (y == 1) ? w2f : w2b;
            u16* dst = (y == 0) ? wt_hh : (y == 1) ? w2ft : w2bt;
            dst[tid] = f2bf(src[g * H_ + k]);
        }
    } else {
        if (tid < 512 * 256) {
            int k = tid / 256;
            int o = tid % 256;
            wc1t[tid] = f2bf(wc1[o * 512 + k]);
        }
    }
}

// ---------------------------------------------------------------------------
// K1: xg[row][g] = sum_d x[n,2,t,d] * w_ih1[g][d] + b_ih1[g]
//     row = n*64 + t, M=32768, K=300, N=768. fp32, 128x128 tile, 8x8/thread.
// ---------------------------------------------------------------------------
template<typename XT>
__global__ __launch_bounds__(256) void k1_xgemm(
    const float* __restrict__ x, const float* __restrict__ wih,
    const float* __restrict__ bih, XT* __restrict__ xg)
{
    const int KT = 12;
    __shared__ float As[KT][132];   // [k][row], padded
    __shared__ float Bs[KT][132];   // [k][col], padded
    int tid = threadIdx.x;
    int tx = tid & 15;              // 16 col-threads (8 cols each)
    int ty = tid >> 4;              // 16 row-threads (8 rows each)
    int row0 = blockIdx.x * 128;
    int col0 = blockIdx.y * 128;
    float c[8][8] = {};

    for (int k0 = 0; k0 < 300; k0 += KT) {
        // stage A: 128 rows x 12 k as float4 triples
        for (int i = tid; i < 128 * 3; i += 256) {
            int r = i / 3, q = i % 3;
            int row = row0 + r;
            int n = row >> 6, t = row & 63;
            const float4 v = *reinterpret_cast<const float4*>(
                &x[(size_t)(n * 256 + 128 + t) * 300 + k0 + q * 4]);
            As[q * 4 + 0][r] = v.x; As[q * 4 + 1][r] = v.y;
            As[q * 4 + 2][r] = v.z; As[q * 4 + 3][r] = v.w;
        }
        // stage B: 128 cols x 12 k
        for (int i = tid; i < 128 * 3; i += 256) {
            int g = i / 3, q = i % 3;
            const float4 v = *reinterpret_cast<const float4*>(
                &wih[(size_t)(col0 + g) * 300 + k0 + q * 4]);
            Bs[q * 4 + 0][g] = v.x; Bs[q * 4 + 1][g] = v.y;
            Bs[q * 4 + 2][g] = v.z; Bs[q * 4 + 3][g] = v.w;
        }
        __syncthreads();
#pragma unroll
        for (int kk = 0; kk < KT; ++kk) {
            float a[8], b[8];
            float4 a0 = *reinterpret_cast<const float4*>(&As[kk][ty * 8]);
            float4 a1 = *reinterpret_cast<const float4*>(&As[kk][ty * 8 + 4]);
            float4 b0 = *reinterpret_cast<const float4*>(&Bs[kk][tx * 8]);
            float4 b1 = *reinterpret_cast<const float4*>(&Bs[kk][tx * 8 + 4]);
            a[0] = a0.x; a[1] = a0.y; a[2] = a0.z; a[3] = a0.w;
            a[4] = a1.x; a[5] = a1.y; a[6] = a1.z; a[7] = a1.w;
            b[0] = b0.x; b[1] = b0.y; b[2] = b0.z; b[3] = b0.w;
            b[4] = b1.x; b[5] = b1.y; b[6] = b1.z; b[7] = b1.w;
#pragma unroll
            for (int i = 0; i < 8; ++i)
#pragma unroll
                for (int j = 0; j < 8; ++j)
                    c[i][j] += a[i] * b[j];
        }
        __syncthreads();
    }

    float bias[8];
#pragma unroll
    for (int j = 0; j < 8; ++j) bias[j] = bih[col0 + tx * 8 + j];
#pragma unroll
    for (int i = 0; i < 8; ++i) {
        int row = row0 + ty * 8 + i;
        float vv[8];
#pragma unroll
        for (int j = 0; j < 8; ++j) vv[j] = c[i][j] + bias[j];
        store8(&xg[(size_t)row * G_ + col0 + tx * 8], vv);
    }
}

// ---------------------------------------------------------------------------
// K2: GRU recurrence. 256 blocks x 2 rows, 64 steps, w_hh bf16 transposed
//     [k][g] streamed from L2 (first KC k-rows cached in LDS).
// ---------------------------------------------------------------------------
template<typename XT>
__global__ __launch_bounds__(256) void k2_gru(
    const XT* __restrict__ xg, const u16* __restrict__ wt,   // [256][768]
    const float* __restrict__ b_hh, float* __restrict__ mid)
{
    const int KC = 32;
    __shared__ u16 wc[KC * G_];       // 48 KB
    __shared__ float h[2][H_];
    __shared__ float hg[2][G_];
    int tid = threadIdx.x;
    int n0 = blockIdx.x * 2;

    for (int i = tid; i < KC * G_ / 2; i += 256)
        ((u32*)wc)[i] = ((const u32*)wt)[i];
    h[0][tid] = 0.f; h[1][tid] = 0.f;
    __syncthreads();

    const int g0 = tid, g1 = tid + 256, g2 = tid + 512;
    const float bh0 = b_hh[g0], bh1 = b_hh[g1], bh2 = b_hh[g2];

    for (int t = 0; t < T_; ++t) {
        const size_t xb0 = ((size_t)(n0 + 0) * T_ + t) * G_;
        const size_t xb1 = ((size_t)(n0 + 1) * T_ + t) * G_;
        float a00 = ldx(xg, xb0 + g0) + bh0;   // r-gate preact
        float a01 = ldx(xg, xb0 + g1) + bh1;   // z-gate preact
        float a02 = bh2;                       // hn (xn kept separate)
        float a10 = ldx(xg, xb1 + g0) + bh0;
        float a11 = ldx(xg, xb1 + g1) + bh1;
        float a12 = bh2;

#pragma unroll 8
        for (int k = 0; k < KC; ++k) {
            float w0 = bf2f(wc[k * G_ + g0]);
            float w1 = bf2f(wc[k * G_ + g1]);
            float w2 = bf2f(wc[k * G_ + g2]);
            float h0 = h[0][k], h1 = h[1][k];
            a00 += h0 * w0; a01 += h0 * w1; a02 += h0 * w2;
            a10 += h1 * w0; a11 += h1 * w1; a12 += h1 * w2;
        }
#pragma unroll 8
        for (int k = KC; k < H_; ++k) {
            float w0 = bf2f(wt[k * G_ + g0]);
            float w1 = bf2f(wt[k * G_ + g1]);
            float w2 = bf2f(wt[k * G_ + g2]);
            float h0 = h[0][k], h1 = h[1][k];
            a00 += h0 * w0; a01 += h0 * w1; a02 += h0 * w2;
            a10 += h1 * w0; a11 += h1 * w1; a12 += h1 * w2;
        }
        hg[0][g0] = a00; hg[0][g1] = a01; hg[0][g2] = a02;
        hg[1][g0] = a10; hg[1][g1] = a11; hg[1][g2] = a12;
        __syncthreads();

        const int j = tid;
        float nh[2];
#pragma unroll
        for (int r = 0; r < 2; ++r) {
            float pr = hg[r][j];
            float pz = hg[r][256 + j];
            float hn = hg[r][512 + j];
            float xn = ldx(xg, ((size_t)(n0 + r) * T_ + t) * G_ + 512 + j);
            float rg = sigm(pr);
            float zg = sigm(pz);
            float ng = tanhf(xn + rg * hn);
            nh[r] = (1.f - zg) * ng + zg * h[r][j];
        }
        h[0][j] = nh[0]; h[1][j] = nh[1];
        __syncthreads();
    }

    mid[(size_t)(n0 + 0) * H_ + tid] = h[0][tid];
    mid[(size_t)(n0 + 1) * H_ + tid] = h[1][tid];
}

// ---------------------------------------------------------------------------
// K3: head. 128 blocks x 4 rows. zero-h GRU cells (w_hh2* unused) + MLP.
// ---------------------------------------------------------------------------
__global__ __launch_bounds__(256) void k3_head(
    const float* __restrict__ mid,
    const u16* __restrict__ w2ft, const u16* __restrict__ w2bt,
    const float* __restrict__ b_ih2f, const float* __restrict__ b_hh2f,
    const float* __restrict__ b_ih2b, const float* __restrict__ b_hh2b,
    const u16* __restrict__ wc1t, const float* __restrict__ bc1,
    const float* __restrict__ wc2, const float* __restrict__ bc2,
    float* __restrict__ out)
{
    __shared__ float m[4][H_];
    __shared__ float xg2[2][4][G_];
    __shared__ float emb[4][512];
    __shared__ float hid[4][H_];
    int tid = threadIdx.x;
    int r0 = blockIdx.x * 4;

    for (int i = tid; i < 4 * H_; i += 256) {
        int r = i >> 8, k = i & 255;
        m[r][k] = mid[(size_t)(r0 + r) * H_ + k];
    }
    __syncthreads();

    // phase 1: xg2 = mid @ w_ih2^T + biases (r,z folded; n keeps b_ih only)
    const int g0 = tid, g1 = tid + 256, g2 = tid + 512;
    float bf0 = b_ih2f[g0] + b_hh2f[g0];
    float bf1 = b_ih2f[g1] + b_hh2f[g1];
    float bf2v = b_ih2f[g2];
    float bb0 = b_ih2b[g0] + b_hh2b[g0];
    float bb1 = b_ih2b[g1] + b_hh2b[g1];
    float bb2v = b_ih2b[g2];
    float af[4][3], ab[4][3];
#pragma unroll
    for (int r = 0; r < 4; ++r) {
        af[r][0] = bf0; af[r][1] = bf1; af[r][2] = bf2v;
        ab[r][0] = bb0; ab[r][1] = bb1; ab[r][2] = bb2v;
    }
#pragma unroll 4
    for (int k = 0; k < H_; ++k) {
        float wf0 = bf2f(w2ft[k * G_ + g0]);
        float wf1 = bf2f(w2ft[k * G_ + g1]);
        float wf2 = bf2f(w2ft[k * G_ + g2]);
        float wb0 = bf2f(w2bt[k * G_ + g0]);
        float wb1 = bf2f(w2bt[k * G_ + g1]);
        float wb2 = bf2f(w2bt[k * G_ + g2]);
#pragma unroll
        for (int r = 0; r < 4; ++r) {
            float mm = m[r][k];
            af[r][0] += mm * wf0; af[r][1] += mm * wf1; af[r][2] += mm * wf2;
            ab[r][0] += mm * wb0; ab[r][1] += mm * wb1; ab[r][2] += mm * wb2;
        }
    }
#pragma unroll
    for (int r = 0; r < 4; ++r) {
        xg2[0][r][g0] = af[r][0]; xg2[0][r][g1] = af[r][1]; xg2[0][r][g2] = af[r][2];
        xg2[1][r][g0] = ab[r][0]; xg2[1][r][g1] = ab[r][1]; xg2[1][r][g2] = ab[r][2];
    }
    __syncthreads();

    // phase 2: gates -> emb = [hf, hb]
    {
        const int j = tid;
        float bnf = b_hh2f[512 + j], bnb = b_hh2b[512 + j];
#pragma unroll
        for (int r = 0; r < 4; ++r) {
            float rg = sigm(xg2[0][r][j]);
            float zg = sigm(xg2[0][r][256 + j]);
            float ng = tanhf(xg2[0][r][512 + j] + rg * bnf);
            emb[r][j] = (1.f - zg) * ng;
            rg = sigm(xg2[1][r][j]);
            zg = sigm(xg2[1][r][256 + j]);
            ng = tanhf(xg2[1][r][512 + j] + rg * bnb);
            emb[r][256 + j] = (1.f - zg) * ng;
        }
    }
    __syncthreads();

    // phase 3: pre = emb @ wc1^T + bc1, leaky-relu
    {
        const int o = tid;
        float acc[4];
        float b = bc1[o];
#pragma unroll
        for (int r = 0; r < 4; ++r) acc[r] = b;
#pragma unroll 4
        for (int k = 0; k < 512; ++k) {
            float w = bf2f(wc1t[k * H_ + o]);
#pragma unroll
            for (int r = 0; r < 4; ++r) acc[r] += emb[r][k] * w;
        }
#pragma unroll
        for (int r = 0; r < 4; ++r) {
            float pre = acc[r];
            hid[r][o] = pre >= 0.f ? pre : 0.1f * pre;
        }
    }
    __syncthreads();

    // phase 4: logits = hid @ wc2^T + bc2 (8 dot-products, 32 lanes each)
    {
        int grp = tid >> 5, lane = tid & 31;
        int r = grp >> 1, cc = grp & 1;
        float s = 0.f;
        for (int k = lane; k < H_; k += 32) s += hid[r][k] * wc2[cc * H_ + k];
#pragma unroll
        for (int msk = 16; msk >= 1; msk >>= 1) s += __shfl_xor(s, msk, 32);
        if (lane == 0) out[(size_t)(r0 + r) * 2 + cc] = s + bc2[cc];
    }
}

// ---------------------------------------------------------------------------
extern "C" void kernel_launch(void* const* d_in, const int* in_sizes, int n_in,
                              void* d_out, int out_size, void* d_ws, size_t ws_size,
                              hipStream_t stream)
{
    const float* x      = (const float*)d_in[0];
    const float* w_ih1  = (const float*)d_in[1];
    const float* w_hh1  = (const float*)d_in[2];
    const float* b_ih1  = (const float*)d_in[3];
    const float* b_hh1  = (const float*)d_in[4];
    const float* w_ih2f = (const float*)d_in[5];
    const float* b_ih2f = (const float*)d_in[7];
    const float* b_hh2f = (const float*)d_in[8];
    const float* w_ih2b = (const float*)d_in[9];
    const float* b_ih2b = (const float*)d_in[11];
    const float* b_hh2b = (const float*)d_in[12];
    const float* wc1    = (const float*)d_in[13];
    const float* bc1    = (const float*)d_in[14];
    const float* wc2    = (const float*)d_in[15];
    const float* bc2    = (const float*)d_in[16];
    float* out = (float*)d_out;

    char* p = (char*)d_ws;
    const size_t xg_f32_bytes = (size_t)M_ * G_ * 4;
    const size_t tail_bytes = 3 * (size_t)G_ * H_ * 2 + (size_t)512 * 256 * 2
                              + (size_t)NROW * H_ * 4;
    const bool xg_is_f32 = ws_size >= xg_f32_bytes + tail_bytes;
    const size_t xg_bytes = xg_is_f32 ? xg_f32_bytes : (size_t)M_ * G_ * 2;

    void* xg   = (void*)p;      p += xg_bytes;
    u16* wt_hh = (u16*)p;       p += (size_t)G_ * H_ * 2;
    u16* w2ft  = (u16*)p;       p += (size_t)G_ * H_ * 2;
    u16* w2bt  = (u16*)p;       p += (size_t)G_ * H_ * 2;
    u16* wc1t  = (u16*)p;       p += (size_t)512 * 256 * 2;
    float* mid = (float*)p;     p += (size_t)NROW * H_ * 4;

    k0_prep<<<dim3(768, 4), 256, 0, stream>>>(w_hh1, w_ih2f, w_ih2b, wc1,
                                              wt_hh, w2ft, w2bt, wc1t);
    if (xg_is_f32) {
        k1_xgemm<float><<<dim3(M_ / 128, G_ / 128), 256, 0, stream>>>(
            x, w_ih1, b_ih1, (float*)xg);
        k2_gru<float><<<NROW / 2, 256, 0, stream>>>(
            (const float*)xg, wt_hh, b_hh1, mid);
    } else {
        k1_xgemm<u16><<<dim3(M_ / 128, G_ / 128), 256, 0, stream>>>(
            x, w_ih1, b_ih1, (u16*)xg);
        k2_gru<u16><<<NROW / 2, 256, 0, stream>>>(
            (const u16*)xg, wt_hh, b_hh1, mid);
    }
    k3_head<<<128, 256, 0, stream>>>(mid, w2ft, w2bt, b_ih2f, b_hh2f,
                                     b_ih2b, b_hh2b, wc1t, bc1, wc2, bc2, out);
}

// Round 3
// 406.080 us; speedup vs baseline: 2.4374x; 2.4374x over previous
//
#include <hip/hip_runtime.h>
#include <hip/hip_bf16.h>

typedef unsigned short u16;
typedef unsigned int u32;
using short8 = __attribute__((ext_vector_type(8))) short;
using f32x4  = __attribute__((ext_vector_type(4))) float;

#define T_   64
#define D_   300
#define H_   256
#define G_   768            // 3H
#define NROW 512            // useful sequences (s==2)
#define M_   (NROW * T_)    // 32768
#define KP_  320            // K=300 padded to 320 for MFMA

__device__ __forceinline__ float bf2f(u16 v) {
    union { u32 u; float f; } x; x.u = ((u32)v) << 16; return x.f;
}
__device__ __forceinline__ u16 f2bf(float f) {
    union { u32 u; float f; } x; x.f = f;
    u32 u = x.u;
    u32 r = (u + 0x7FFFu + ((u >> 16) & 1u)) >> 16;   // RNE
    return (u16)r;
}
__device__ __forceinline__ float sigm(float x) { return 1.f / (1.f + expf(-x)); }

// ---------------------------------------------------------------------------
// K0: weight prep.
//  y=0: w_ih1 (768x300 f32) -> wihb [768][320] bf16, zero-padded k>=300
//  y=1: w_hh1 (768x256 f32) -> whpk: MFMA B-frag-packed [nt 0..47][ks 0..7][lane][e]
//       value = W[k][g] = w_hh1[g*256+k], g = nt*16+(lane&15), k = ks*32+(lane>>4)*8+e
//  y=2: w_ih2f -> w2ft [256][768] bf16 (transposed)
//  y=3: w_ih2b -> w2bt [256][768] bf16 (transposed)
//  y=4: wc1    -> wc1t [512][256] bf16 (transposed)
// ---------------------------------------------------------------------------
__global__ __launch_bounds__(256) void k0_prep(
    const float* __restrict__ w_ih1, const float* __restrict__ w_hh1,
    const float* __restrict__ w2f, const float* __restrict__ w2b,
    const float* __restrict__ wc1,
    u16* __restrict__ wihb, u16* __restrict__ whpk,
    u16* __restrict__ w2ft, u16* __restrict__ w2bt, u16* __restrict__ wc1t)
{
    int y = blockIdx.y;
    int tid = blockIdx.x * 256 + threadIdx.x;
    if (y == 0) {
        if (tid < G_ * KP_) {
            int g = tid / KP_, k = tid % KP_;
            wihb[tid] = (k < D_) ? f2bf(w_ih1[g * D_ + k]) : (u16)0;
        }
    } else if (y == 1) {
        if (tid < 48 * 8 * 64) {
            int lane = tid & 63;
            int ks = (tid >> 6) & 7;
            int nt = tid >> 9;
            int g  = nt * 16 + (lane & 15);
            int kb = ks * 32 + ((lane >> 4) << 3);
            union { u16 h[8]; uint4 q; } u;
#pragma unroll
            for (int e = 0; e < 8; ++e) u.h[e] = f2bf(w_hh1[g * H_ + kb + e]);
            *reinterpret_cast<uint4*>(&whpk[(size_t)tid * 8]) = u.q;
        }
    } else if (y == 2 || y == 3) {
        if (tid < G_ * H_) {
            int k = tid / G_, g = tid % G_;
            const float* src = (y == 2) ? w2f : w2b;
            u16* dst = (y == 2) ? w2ft : w2bt;
            dst[tid] = f2bf(src[g * H_ + k]);
        }
    } else {
        if (tid < 512 * 256) {
            int k = tid / 256, o = tid % 256;
            wc1t[tid] = f2bf(wc1[o * 512 + k]);
        }
    }
}

// ---------------------------------------------------------------------------
// K1: xg = x[:,2] @ w_ih1^T + b_ih1 via bf16 MFMA. M=32768 N=768 K=320(pad).
//     128x128 tile, 256 thr (4 waves 2x2), BK=32 (one 16x16x32 k-step).
// ---------------------------------------------------------------------------
__global__ __launch_bounds__(256) void k1_xgemm(
    const float* __restrict__ x, const u16* __restrict__ wihb,
    const float* __restrict__ bih, u16* __restrict__ xg)
{
    __shared__ alignas(16) u16 As[128 * 40];   // stride 40 shorts (80B)
    __shared__ alignas(16) u16 Bs[128 * 40];
    const int tid = threadIdx.x;
    const int l = tid & 63, wv = tid >> 6;
    const int wrow = wv >> 1, wcol = wv & 1;
    const int row0 = blockIdx.x * 128, col0 = blockIdx.y * 128;

    f32x4 acc[4][4];
#pragma unroll
    for (int i = 0; i < 4; ++i)
#pragma unroll
        for (int j = 0; j < 4; ++j) acc[i][j] = (f32x4){0.f, 0.f, 0.f, 0.f};

    const int ar = tid >> 1, ah = tid & 1;
    const int grow = row0 + ar;
    const int n = grow >> 6, t = grow & 63;
    const float* xrow = x + (size_t)(n * 256 + 128 + t) * D_;
    const u16* wrowp = wihb + (size_t)(col0 + ar) * KP_;

    for (int k0 = 0; k0 < KP_; k0 += 32) {
        // ---- stage A (fp32 -> bf16), 16 shorts/thread ----
        union { u16 h[16]; uint4 q[2]; } u;
        const int kb = k0 + ah * 16;
        if (kb + 15 < D_) {
            const float4 v0 = *reinterpret_cast<const float4*>(xrow + kb);
            const float4 v1 = *reinterpret_cast<const float4*>(xrow + kb + 4);
            const float4 v2 = *reinterpret_cast<const float4*>(xrow + kb + 8);
            const float4 v3 = *reinterpret_cast<const float4*>(xrow + kb + 12);
            u.h[0] = f2bf(v0.x); u.h[1] = f2bf(v0.y); u.h[2] = f2bf(v0.z); u.h[3] = f2bf(v0.w);
            u.h[4] = f2bf(v1.x); u.h[5] = f2bf(v1.y); u.h[6] = f2bf(v1.z); u.h[7] = f2bf(v1.w);
            u.h[8] = f2bf(v2.x); u.h[9] = f2bf(v2.y); u.h[10] = f2bf(v2.z); u.h[11] = f2bf(v2.w);
            u.h[12] = f2bf(v3.x); u.h[13] = f2bf(v3.y); u.h[14] = f2bf(v3.z); u.h[15] = f2bf(v3.w);
        } else {
#pragma unroll
            for (int e = 0; e < 16; ++e) {
                int k = kb + e;
                u.h[e] = (k < D_) ? f2bf(xrow[k]) : (u16)0;
            }
        }
        *reinterpret_cast<uint4*>(&As[ar * 40 + ah * 16]) = u.q[0];
        *reinterpret_cast<uint4*>(&As[ar * 40 + ah * 16 + 8]) = u.q[1];
        // ---- stage B (already bf16), 16 shorts/thread (BUG FIX: was 8) ----
        *reinterpret_cast<uint4*>(&Bs[ar * 40 + ah * 16]) =
            *reinterpret_cast<const uint4*>(wrowp + k0 + ah * 16);
        *reinterpret_cast<uint4*>(&Bs[ar * 40 + ah * 16 + 8]) =
            *reinterpret_cast<const uint4*>(wrowp + k0 + ah * 16 + 8);
        __syncthreads();

        short8 af[4], bf[4];
#pragma unroll
        for (int fi = 0; fi < 4; ++fi)
            af[fi] = *reinterpret_cast<const short8*>(
                &As[(wrow * 64 + fi * 16 + (l & 15)) * 40 + ((l >> 4) << 3)]);
#pragma unroll
        for (int fj = 0; fj < 4; ++fj)
            bf[fj] = *reinterpret_cast<const short8*>(
                &Bs[(wcol * 64 + fj * 16 + (l & 15)) * 40 + ((l >> 4) << 3)]);
#pragma unroll
        for (int fi = 0; fi < 4; ++fi)
#pragma unroll
            for (int fj = 0; fj < 4; ++fj)
                acc[fi][fj] = __builtin_amdgcn_mfma_f32_16x16x32_bf16(
                    af[fi], bf[fj], acc[fi][fj], 0, 0, 0);
        __syncthreads();
    }

    float bias[4];
#pragma unroll
    for (int fj = 0; fj < 4; ++fj)
        bias[fj] = bih[col0 + wcol * 64 + fj * 16 + (l & 15)];
#pragma unroll
    for (int fi = 0; fi < 4; ++fi)
#pragma unroll
        for (int fj = 0; fj < 4; ++fj)
#pragma unroll
            for (int q = 0; q < 4; ++q) {
                int row = row0 + wrow * 64 + fi * 16 + ((l >> 4) << 2) + q;
                int col = col0 + wcol * 64 + fj * 16 + (l & 15);
                xg[(size_t)row * G_ + col] = f2bf(acc[fi][fj][q] + bias[fj]);
            }
}

// ---------------------------------------------------------------------------
// K2: GRU recurrence, MFMA with w_hh persistent in registers.
//     32 blocks x 16 rows, 512 thr (8 waves). Wave w owns hidden units
//     [32w, 32w+32) across all 3 gate types -> gate update is wave-local.
// ---------------------------------------------------------------------------
__global__ __launch_bounds__(512, 2) void k2_gru(
    const u16* __restrict__ xg, const u16* __restrict__ whpk,
    const float* __restrict__ b_hh, float* __restrict__ mid)
{
    __shared__ alignas(16) u16 hb[16 * 264];   // bf16 h, row stride 264 (528B)
    __shared__ float hf[16 * 257];             // f32 h, row stride 257
    const int tid = threadIdx.x;
    const int l = tid & 63, wv = tid >> 6;
    const int n0 = blockIdx.x * 16;

    // load persistent weights: tile (gt,a): nt = gt*16 + wv*2 + a
    short8 wreg[3][2][8];
#pragma unroll
    for (int gt = 0; gt < 3; ++gt)
#pragma unroll
        for (int a = 0; a < 2; ++a) {
            const int nt = gt * 16 + wv * 2 + a;
#pragma unroll
            for (int ks = 0; ks < 8; ++ks)
                wreg[gt][a][ks] = *reinterpret_cast<const short8*>(
                    &whpk[(size_t)((nt * 8 + ks) * 64 + l) * 8]);
        }

    for (int i = tid; i < 16 * 264; i += 512) hb[i] = 0;
    for (int i = tid; i < 16 * 257; i += 512) hf[i] = 0.f;

    // per-thread gate metadata: unit j(a) = wv*32 + a*16 + (l&15)
    float bhr[2], bhz[2], bhn[2];
    int ju[2];
#pragma unroll
    for (int a = 0; a < 2; ++a) {
        ju[a] = wv * 32 + a * 16 + (l & 15);
        bhr[a] = b_hh[ju[a]];
        bhz[a] = b_hh[256 + ju[a]];
        bhn[a] = b_hh[512 + ju[a]];
    }
    const int rbase = (l >> 4) << 2;   // D rows rbase..rbase+3

    __syncthreads();

    for (int t = 0; t < T_; ++t) {
        // prefetch this step's xg (independent of h) — overlaps MFMA
        float xv[3][2][4];
#pragma unroll
        for (int a = 0; a < 2; ++a)
#pragma unroll
            for (int q = 0; q < 4; ++q) {
                const u32 off = ((u32)(n0 + rbase + q) * T_ + t) * G_ + ju[a];
                xv[0][a][q] = bf2f(xg[off]);
                xv[1][a][q] = bf2f(xg[off + 256]);
                xv[2][a][q] = bf2f(xg[off + 512]);
            }

        // MFMA phase: hg = h @ W for this wave's 6 tiles
        f32x4 acc[3][2];
#pragma unroll
        for (int gt = 0; gt < 3; ++gt)
#pragma unroll
            for (int a = 0; a < 2; ++a) acc[gt][a] = (f32x4){0.f, 0.f, 0.f, 0.f};
#pragma unroll
        for (int ks = 0; ks < 8; ++ks) {
            const short8 afr = *reinterpret_cast<const short8*>(
                &hb[(l & 15) * 264 + ks * 32 + ((l >> 4) << 3)]);
#pragma unroll
            for (int gt = 0; gt < 3; ++gt)
#pragma unroll
                for (int a = 0; a < 2; ++a)
                    acc[gt][a] = __builtin_amdgcn_mfma_f32_16x16x32_bf16(
                        afr, wreg[gt][a][ks], acc[gt][a], 0, 0, 0);
        }
        __syncthreads();   // all A-frag reads of h_t done

        // update phase: wave-local gates for 8 (row,unit) pairs
#pragma unroll
        for (int a = 0; a < 2; ++a)
#pragma unroll
            for (int q = 0; q < 4; ++q) {
                const int row = rbase + q;
                const float pr = xv[0][a][q] + acc[0][a][q] + bhr[a];
                const float pz = xv[1][a][q] + acc[1][a][q] + bhz[a];
                const float hn = acc[2][a][q] + bhn[a];
                const float rg = sigm(pr);
                const float zg = sigm(pz);
                const float ng = tanhf(xv[2][a][q] + rg * hn);
                const float ho = hf[row * 257 + ju[a]];
                const float hw = (1.f - zg) * ng + zg * ho;
                hf[row * 257 + ju[a]] = hw;
                hb[row * 264 + ju[a]] = f2bf(hw);
            }
        __syncthreads();   // h_{t+1} visible to all waves
    }

    for (int i = tid; i < 16 * 256; i += 512) {
        int row = i >> 8, j = i & 255;
        mid[(size_t)(n0 + row) * H_ + j] = hf[row * 257 + j];
    }
}

// ---------------------------------------------------------------------------
// K3: head. 128 blocks x 4 rows. zero-h GRU cells (w_hh2* matmuls vanish) + MLP.
// ---------------------------------------------------------------------------
__global__ __launch_bounds__(256) void k3_head(
    const float* __restrict__ mid,
    const u16* __restrict__ w2ft, const u16* __restrict__ w2bt,
    const float* __restrict__ b_ih2f, const float* __restrict__ b_hh2f,
    const float* __restrict__ b_ih2b, const float* __restrict__ b_hh2b,
    const u16* __restrict__ wc1t, const float* __restrict__ bc1,
    const float* __restrict__ wc2, const float* __restrict__ bc2,
    float* __restrict__ out)
{
    __shared__ float m[4][H_];
    __shared__ float xg2[2][4][G_];
    __shared__ float emb[4][512];
    __shared__ float hid[4][H_];
    int tid = threadIdx.x;
    int r0 = blockIdx.x * 4;

    for (int i = tid; i < 4 * H_; i += 256) {
        int r = i >> 8, k = i & 255;
        m[r][k] = mid[(size_t)(r0 + r) * H_ + k];
    }
    __syncthreads();

    const int g0 = tid, g1 = tid + 256, g2 = tid + 512;
    float bf0 = b_ih2f[g0] + b_hh2f[g0];
    float bf1 = b_ih2f[g1] + b_hh2f[g1];
    float bf2v = b_ih2f[g2];
    float bb0 = b_ih2b[g0] + b_hh2b[g0];
    float bb1 = b_ih2b[g1] + b_hh2b[g1];
    float bb2v = b_ih2b[g2];
    float af[4][3], ab[4][3];
#pragma unroll
    for (int r = 0; r < 4; ++r) {
        af[r][0] = bf0; af[r][1] = bf1; af[r][2] = bf2v;
        ab[r][0] = bb0; ab[r][1] = bb1; ab[r][2] = bb2v;
    }
#pragma unroll 4
    for (int k = 0; k < H_; ++k) {
        float wf0 = bf2f(w2ft[k * G_ + g0]);
        float wf1 = bf2f(w2ft[k * G_ + g1]);
        float wf2 = bf2f(w2ft[k * G_ + g2]);
        float wb0 = bf2f(w2bt[k * G_ + g0]);
        float wb1 = bf2f(w2bt[k * G_ + g1]);
        float wb2 = bf2f(w2bt[k * G_ + g2]);
#pragma unroll
        for (int r = 0; r < 4; ++r) {
            float mm = m[r][k];
            af[r][0] += mm * wf0; af[r][1] += mm * wf1; af[r][2] += mm * wf2;
            ab[r][0] += mm * wb0; ab[r][1] += mm * wb1; ab[r][2] += mm * wb2;
        }
    }
#pragma unroll
    for (int r = 0; r < 4; ++r) {
        xg2[0][r][g0] = af[r][0]; xg2[0][r][g1] = af[r][1]; xg2[0][r][g2] = af[r][2];
        xg2[1][r][g0] = ab[r][0]; xg2[1][r][g1] = ab[r][1]; xg2[1][r][g2] = ab[r][2];
    }
    __syncthreads();

    {
        const int j = tid;
        float bnf = b_hh2f[512 + j], bnb = b_hh2b[512 + j];
#pragma unroll
        for (int r = 0; r < 4; ++r) {
            float rg = sigm(xg2[0][r][j]);
            float zg = sigm(xg2[0][r][256 + j]);
            float ng = tanhf(xg2[0][r][512 + j] + rg * bnf);
            emb[r][j] = (1.f - zg) * ng;
            rg = sigm(xg2[1][r][j]);
            zg = sigm(xg2[1][r][256 + j]);
            ng = tanhf(xg2[1][r][512 + j] + rg * bnb);
            emb[r][256 + j] = (1.f - zg) * ng;
        }
    }
    __syncthreads();

    {
        const int o = tid;
        float acc[4];
        float b = bc1[o];
#pragma unroll
        for (int r = 0; r < 4; ++r) acc[r] = b;
#pragma unroll 4
        for (int k = 0; k < 512; ++k) {
            float w = bf2f(wc1t[k * H_ + o]);
#pragma unroll
            for (int r = 0; r < 4; ++r) acc[r] += emb[r][k] * w;
        }
#pragma unroll
        for (int r = 0; r < 4; ++r) {
            float pre = acc[r];
            hid[r][o] = pre >= 0.f ? pre : 0.1f * pre;
        }
    }
    __syncthreads();

    {
        int grp = tid >> 5, lane = tid & 31;
        int r = grp >> 1, cc = grp & 1;
        float s = 0.f;
        for (int k = lane; k < H_; k += 32) s += hid[r][k] * wc2[cc * H_ + k];
#pragma unroll
        for (int msk = 16; msk >= 1; msk >>= 1) s += __shfl_xor(s, msk, 32);
        if (lane == 0) out[(size_t)(r0 + r) * 2 + cc] = s + bc2[cc];
    }
}

// ---------------------------------------------------------------------------
extern "C" void kernel_launch(void* const* d_in, const int* in_sizes, int n_in,
                              void* d_out, int out_size, void* d_ws, size_t ws_size,
                              hipStream_t stream)
{
    const float* x      = (const float*)d_in[0];
    const float* w_ih1  = (const float*)d_in[1];
    const float* w_hh1  = (const float*)d_in[2];
    const float* b_ih1  = (const float*)d_in[3];
    const float* b_hh1  = (const float*)d_in[4];
    const float* w_ih2f = (const float*)d_in[5];
    const float* b_ih2f = (const float*)d_in[7];
    const float* b_hh2f = (const float*)d_in[8];
    const float* w_ih2b = (const float*)d_in[9];
    const float* b_ih2b = (const float*)d_in[11];
    const float* b_hh2b = (const float*)d_in[12];
    const float* wc1    = (const float*)d_in[13];
    const float* bc1    = (const float*)d_in[14];
    const float* wc2    = (const float*)d_in[15];
    const float* bc2    = (const float*)d_in[16];
    float* out = (float*)d_out;

    char* p = (char*)d_ws;
    u16* xg   = (u16*)p;  p += (size_t)M_ * G_ * 2;        // 48 MB
    u16* wihb = (u16*)p;  p += (size_t)G_ * KP_ * 2;       // 480 KB
    u16* whpk = (u16*)p;  p += (size_t)48 * 8 * 64 * 8 * 2; // 384 KB
    u16* w2ft = (u16*)p;  p += (size_t)G_ * H_ * 2;
    u16* w2bt = (u16*)p;  p += (size_t)G_ * H_ * 2;
    u16* wc1t = (u16*)p;  p += (size_t)512 * 256 * 2;
    float* mid = (float*)p; p += (size_t)NROW * H_ * 4;

    k0_prep<<<dim3(960, 5), 256, 0, stream>>>(w_ih1, w_hh1, w_ih2f, w_ih2b, wc1,
                                              wihb, whpk, w2ft, w2bt, wc1t);
    k1_xgemm<<<dim3(M_ / 128, G_ / 128), 256, 0, stream>>>(x, wihb, b_ih1, xg);
    k2_gru<<<32, 512, 0, stream>>>(xg, whpk, b_hh1, mid);
    k3_head<<<128, 256, 0, stream>>>(mid, w2ft, w2bt, b_ih2f, b_hh2f,
                                     b_ih2b, b_hh2b, wc1t, bc1, wc2, bc2, out);
}

// Round 4
// 383.905 us; speedup vs baseline: 2.5782x; 1.0578x over previous
//
#include <hip/hip_runtime.h>
#include <hip/hip_bf16.h>

typedef unsigned short u16;
typedef unsigned int u32;
using short8 = __attribute__((ext_vector_type(8))) short;
using f32x4  = __attribute__((ext_vector_type(4))) float;

#define T_   64
#define D_   300
#define H_   256
#define G_   768            // 3H
#define NROW 512            // useful sequences (s==2)
#define M_   (NROW * T_)    // 32768
#define KP_  320            // K=300 padded to 320 for MFMA

__device__ __forceinline__ float bf2f(u16 v) {
    union { u32 u; float f; } x; x.u = ((u32)v) << 16; return x.f;
}
__device__ __forceinline__ u16 f2bf(float f) {
    union { u32 u; float f; } x; x.f = f;
    u32 u = x.u;
    u32 r = (u + 0x7FFFu + ((u >> 16) & 1u)) >> 16;   // RNE
    return (u16)r;
}
__device__ __forceinline__ float frcp(float x) {
    float r; asm("v_rcp_f32 %0, %1" : "=v"(r) : "v"(x)); return r;
}
// saturating fast sigmoid / tanh (exp overflow -> inf -> rcp -> 0: correct limits)
__device__ __forceinline__ float fsigm(float x) { return frcp(1.f + __expf(-x)); }
__device__ __forceinline__ float ftanh(float x) {
    return 1.f - 2.f * frcp(1.f + __expf(2.f * x));
}
__device__ __forceinline__ float sigm(float x) { return 1.f / (1.f + expf(-x)); }

// ---------------------------------------------------------------------------
// K0: weight prep. (unchanged from round 3)
// ---------------------------------------------------------------------------
__global__ __launch_bounds__(256) void k0_prep(
    const float* __restrict__ w_ih1, const float* __restrict__ w_hh1,
    const float* __restrict__ w2f, const float* __restrict__ w2b,
    const float* __restrict__ wc1,
    u16* __restrict__ wihb, u16* __restrict__ whpk,
    u16* __restrict__ w2ft, u16* __restrict__ w2bt, u16* __restrict__ wc1t)
{
    int y = blockIdx.y;
    int tid = blockIdx.x * 256 + threadIdx.x;
    if (y == 0) {
        if (tid < G_ * KP_) {
            int g = tid / KP_, k = tid % KP_;
            wihb[tid] = (k < D_) ? f2bf(w_ih1[g * D_ + k]) : (u16)0;
        }
    } else if (y == 1) {
        if (tid < 48 * 8 * 64) {
            int lane = tid & 63;
            int ks = (tid >> 6) & 7;
            int nt = tid >> 9;
            int g  = nt * 16 + (lane & 15);
            int kb = ks * 32 + ((lane >> 4) << 3);
            union { u16 h[8]; uint4 q; } u;
#pragma unroll
            for (int e = 0; e < 8; ++e) u.h[e] = f2bf(w_hh1[g * H_ + kb + e]);
            *reinterpret_cast<uint4*>(&whpk[(size_t)tid * 8]) = u.q;
        }
    } else if (y == 2 || y == 3) {
        if (tid < G_ * H_) {
            int k = tid / G_, g = tid % G_;
            const float* src = (y == 2) ? w2f : w2b;
            u16* dst = (y == 2) ? w2ft : w2bt;
            dst[tid] = f2bf(src[g * H_ + k]);
        }
    } else {
        if (tid < 512 * 256) {
            int k = tid / 256, o = tid % 256;
            wc1t[tid] = f2bf(wc1[o * 512 + k]);
        }
    }
}

// ---------------------------------------------------------------------------
// K1: xg = x[:,2] @ w_ih1^T + b_ih1 via bf16 MFMA. (unchanged from round 3)
// ---------------------------------------------------------------------------
__global__ __launch_bounds__(256) void k1_xgemm(
    const float* __restrict__ x, const u16* __restrict__ wihb,
    const float* __restrict__ bih, u16* __restrict__ xg)
{
    __shared__ alignas(16) u16 As[128 * 40];
    __shared__ alignas(16) u16 Bs[128 * 40];
    const int tid = threadIdx.x;
    const int l = tid & 63, wv = tid >> 6;
    const int wrow = wv >> 1, wcol = wv & 1;
    const int row0 = blockIdx.x * 128, col0 = blockIdx.y * 128;

    f32x4 acc[4][4];
#pragma unroll
    for (int i = 0; i < 4; ++i)
#pragma unroll
        for (int j = 0; j < 4; ++j) acc[i][j] = (f32x4){0.f, 0.f, 0.f, 0.f};

    const int ar = tid >> 1, ah = tid & 1;
    const int grow = row0 + ar;
    const int n = grow >> 6, t = grow & 63;
    const float* xrow = x + (size_t)(n * 256 + 128 + t) * D_;
    const u16* wrowp = wihb + (size_t)(col0 + ar) * KP_;

    for (int k0 = 0; k0 < KP_; k0 += 32) {
        union { u16 h[16]; uint4 q[2]; } u;
        const int kb = k0 + ah * 16;
        if (kb + 15 < D_) {
            const float4 v0 = *reinterpret_cast<const float4*>(xrow + kb);
            const float4 v1 = *reinterpret_cast<const float4*>(xrow + kb + 4);
            const float4 v2 = *reinterpret_cast<const float4*>(xrow + kb + 8);
            const float4 v3 = *reinterpret_cast<const float4*>(xrow + kb + 12);
            u.h[0] = f2bf(v0.x); u.h[1] = f2bf(v0.y); u.h[2] = f2bf(v0.z); u.h[3] = f2bf(v0.w);
            u.h[4] = f2bf(v1.x); u.h[5] = f2bf(v1.y); u.h[6] = f2bf(v1.z); u.h[7] = f2bf(v1.w);
            u.h[8] = f2bf(v2.x); u.h[9] = f2bf(v2.y); u.h[10] = f2bf(v2.z); u.h[11] = f2bf(v2.w);
            u.h[12] = f2bf(v3.x); u.h[13] = f2bf(v3.y); u.h[14] = f2bf(v3.z); u.h[15] = f2bf(v3.w);
        } else {
#pragma unroll
            for (int e = 0; e < 16; ++e) {
                int k = kb + e;
                u.h[e] = (k < D_) ? f2bf(xrow[k]) : (u16)0;
            }
        }
        *reinterpret_cast<uint4*>(&As[ar * 40 + ah * 16]) = u.q[0];
        *reinterpret_cast<uint4*>(&As[ar * 40 + ah * 16 + 8]) = u.q[1];
        *reinterpret_cast<uint4*>(&Bs[ar * 40 + ah * 16]) =
            *reinterpret_cast<const uint4*>(wrowp + k0 + ah * 16);
        *reinterpret_cast<uint4*>(&Bs[ar * 40 + ah * 16 + 8]) =
            *reinterpret_cast<const uint4*>(wrowp + k0 + ah * 16 + 8);
        __syncthreads();

        short8 af[4], bf[4];
#pragma unroll
        for (int fi = 0; fi < 4; ++fi)
            af[fi] = *reinterpret_cast<const short8*>(
                &As[(wrow * 64 + fi * 16 + (l & 15)) * 40 + ((l >> 4) << 3)]);
#pragma unroll
        for (int fj = 0; fj < 4; ++fj)
            bf[fj] = *reinterpret_cast<const short8*>(
                &Bs[(wcol * 64 + fj * 16 + (l & 15)) * 40 + ((l >> 4) << 3)]);
#pragma unroll
        for (int fi = 0; fi < 4; ++fi)
#pragma unroll
            for (int fj = 0; fj < 4; ++fj)
                acc[fi][fj] = __builtin_amdgcn_mfma_f32_16x16x32_bf16(
                    af[fi], bf[fj], acc[fi][fj], 0, 0, 0);
        __syncthreads();
    }

    float bias[4];
#pragma unroll
    for (int fj = 0; fj < 4; ++fj)
        bias[fj] = bih[col0 + wcol * 64 + fj * 16 + (l & 15)];
#pragma unroll
    for (int fi = 0; fi < 4; ++fi)
#pragma unroll
        for (int fj = 0; fj < 4; ++fj)
#pragma unroll
            for (int q = 0; q < 4; ++q) {
                int row = row0 + wrow * 64 + fi * 16 + ((l >> 4) << 2) + q;
                int col = col0 + wcol * 64 + fj * 16 + (l & 15);
                xg[(size_t)row * G_ + col] = f2bf(acc[fi][fj][q] + bias[fj]);
            }
}

// ---------------------------------------------------------------------------
// K2 v2: 32 blocks x 1024 thr (16 waves). Wave w owns units [16w,16w+16)
// for all 3 gates (tiles w, 16+w, 32+w). Weights: ks0-5 in regs (72 VGPR),
// ks6-7 in LDS (96KB). h master in regs; bf16 h in LDS for A-frags.
// Raw s_barrier + lgkmcnt(0) only — xg prefetch 1 step ahead crosses barriers.
// ---------------------------------------------------------------------------
__device__ __forceinline__ void gru_step(
    const u16* __restrict__ xg, const u16* wl, u16* hb,
    const short8 (&wreg)[3][6], const u32 (&xoff)[4], const float (&bh)[3],
    float (&h)[4], u32 (&xv_cur)[3][4], u32 (&xv_nxt)[3][4],
    int tload, int l, int wv, int rgrp, int u)
{
    const int arow = l & 15;            // A-frag row
    const int klo  = (l >> 4) << 3;     // A-frag k-offset within 32-chunk

    // prefetch next step's xg gate values (cross barriers; vmcnt counted)
#pragma unroll
    for (int q = 0; q < 4; ++q) {
        const u32 b = xoff[q] + (u32)tload * G_;
        xv_nxt[0][q] = xg[b];
        xv_nxt[1][q] = xg[b + 256];
        xv_nxt[2][q] = xg[b + 512];
    }

    // MFMA phase: hg = h @ W for this wave's 3 gate tiles
    f32x4 acc0 = (f32x4){0.f,0.f,0.f,0.f};
    f32x4 acc1 = (f32x4){0.f,0.f,0.f,0.f};
    f32x4 acc2 = (f32x4){0.f,0.f,0.f,0.f};
    __builtin_amdgcn_s_setprio(1);
#pragma unroll
    for (int ks = 0; ks < 8; ++ks) {
        const short8 afr = *reinterpret_cast<const short8*>(
            &hb[arow * 264 + ks * 32 + klo]);
        short8 b0, b1, b2;
        if (ks < 6) {
            b0 = wreg[0][ks]; b1 = wreg[1][ks]; b2 = wreg[2][ks];
        } else {
            b0 = *reinterpret_cast<const short8*>(
                &wl[(size_t)(((wv) * 2 + (ks - 6)) * 64 + l) * 8]);
            b1 = *reinterpret_cast<const short8*>(
                &wl[(size_t)(((16 + wv) * 2 + (ks - 6)) * 64 + l) * 8]);
            b2 = *reinterpret_cast<const short8*>(
                &wl[(size_t)(((32 + wv) * 2 + (ks - 6)) * 64 + l) * 8]);
        }
        acc0 = __builtin_amdgcn_mfma_f32_16x16x32_bf16(afr, b0, acc0, 0, 0, 0);
        acc1 = __builtin_amdgcn_mfma_f32_16x16x32_bf16(afr, b1, acc1, 0, 0, 0);
        acc2 = __builtin_amdgcn_mfma_f32_16x16x32_bf16(afr, b2, acc2, 0, 0, 0);
    }
    __builtin_amdgcn_s_setprio(0);

    // B1: all waves done READING hb (lgkm only; global loads stay in flight)
    asm volatile("s_waitcnt lgkmcnt(0)" ::: "memory");
    __builtin_amdgcn_sched_barrier(0);
    __builtin_amdgcn_s_barrier();
    __builtin_amdgcn_sched_barrier(0);

    // update phase (wave-local): 4 (row,unit) pairs per lane
#pragma unroll
    for (int q = 0; q < 4; ++q) {
        const float xr = bf2f((u16)xv_cur[0][q]);
        const float xz = bf2f((u16)xv_cur[1][q]);
        const float xn = bf2f((u16)xv_cur[2][q]);
        const float rg = fsigm(xr + acc0[q] + bh[0]);
        const float zg = fsigm(xz + acc1[q] + bh[1]);
        const float hn = acc2[q] + bh[2];
        const float ng = ftanh(xn + rg * hn);
        h[q] = zg * (h[q] - ng) + ng;
        hb[(rgrp * 4 + q) * 264 + u] = f2bf(h[q]);
    }

    // B2: writes visible before next step's reads
    asm volatile("s_waitcnt lgkmcnt(0)" ::: "memory");
    __builtin_amdgcn_sched_barrier(0);
    __builtin_amdgcn_s_barrier();
    __builtin_amdgcn_sched_barrier(0);
}

__global__ __launch_bounds__(1024, 4) void k2_gru(
    const u16* __restrict__ xg, const u16* __restrict__ whpk,
    const float* __restrict__ b_hh, float* __restrict__ mid)
{
    extern __shared__ u16 smem[];
    u16* wl = smem;                        // 48*2*64*8 u16 = 98304 B
    u16* hb = smem + 48 * 2 * 64 * 8;      // 16*264 u16 = 8448 B
    const int tid = threadIdx.x;
    const int l = tid & 63, wv = tid >> 6;   // wv in [0,16)
    const int n0 = blockIdx.x * 16;
    const int col = l & 15;
    const int rgrp = l >> 4;
    const int u = wv * 16 + col;

    // persistent weights ks 0..5 (72 VGPR)
    short8 wreg[3][6];
#pragma unroll
    for (int gt = 0; gt < 3; ++gt) {
        const int nt = gt * 16 + wv;
#pragma unroll
        for (int ks = 0; ks < 6; ++ks)
            wreg[gt][ks] = *reinterpret_cast<const short8*>(
                &whpk[(size_t)((nt * 8 + ks) * 64 + l) * 8]);
    }
    // stage ks 6..7 into LDS
    for (int c = tid; c < 48 * 2 * 64; c += 1024) {
        const int nt = c >> 7, j = (c >> 6) & 1, ll = c & 63;
        *reinterpret_cast<uint4*>(&wl[(size_t)c * 8]) =
            *reinterpret_cast<const uint4*>(
                &whpk[(size_t)((nt * 8 + 6 + j) * 64 + ll) * 8]);
    }
    for (int i = tid; i < 16 * 264 / 2; i += 1024) ((u32*)hb)[i] = 0;

    const float bh[3] = { b_hh[u], b_hh[256 + u], b_hh[512 + u] };
    float h[4] = {0.f, 0.f, 0.f, 0.f};

    u32 xoff[4];
#pragma unroll
    for (int q = 0; q < 4; ++q)
        xoff[q] = ((u32)(n0 + rgrp * 4 + q) * T_) * G_ + u;

    __syncthreads();

    // prologue: load t=0 gates
    u32 xvA[3][4], xvB[3][4];
#pragma unroll
    for (int q = 0; q < 4; ++q) {
        const u32 b = xoff[q];
        xvA[0][q] = xg[b]; xvA[1][q] = xg[b + 256]; xvA[2][q] = xg[b + 512];
    }

    for (int t = 0; t < T_; t += 2) {
        const int t1 = (t + 1 < T_ - 1) ? t + 1 : T_ - 1;
        const int t2 = (t + 2 < T_ - 1) ? t + 2 : T_ - 1;
        gru_step(xg, wl, hb, wreg, xoff, bh, h, xvA, xvB, t1, l, wv, rgrp, u);
        gru_step(xg, wl, hb, wreg, xoff, bh, h, xvB, xvA, t2, l, wv, rgrp, u);
    }

#pragma unroll
    for (int q = 0; q < 4; ++q)
        mid[(size_t)(n0 + rgrp * 4 + q) * H_ + u] = h[q];
}

// ---------------------------------------------------------------------------
// K3: head. (unchanged from round 3)
// ---------------------------------------------------------------------------
__global__ __launch_bounds__(256) void k3_head(
    const float* __restrict__ mid,
    const u16* __restrict__ w2ft, const u16* __restrict__ w2bt,
    const float* __restrict__ b_ih2f, const float* __restrict__ b_hh2f,
    const float* __restrict__ b_ih2b, const float* __restrict__ b_hh2b,
    const u16* __restrict__ wc1t, const float* __restrict__ bc1,
    const float* __restrict__ wc2, const float* __restrict__ bc2,
    float* __restrict__ out)
{
    __shared__ float m[4][H_];
    __shared__ float xg2[2][4][G_];
    __shared__ float emb[4][512];
    __shared__ float hid[4][H_];
    int tid = threadIdx.x;
    int r0 = blockIdx.x * 4;

    for (int i = tid; i < 4 * H_; i += 256) {
        int r = i >> 8, k = i & 255;
        m[r][k] = mid[(size_t)(r0 + r) * H_ + k];
    }
    __syncthreads();

    const int g0 = tid, g1 = tid + 256, g2 = tid + 512;
    float bf0 = b_ih2f[g0] + b_hh2f[g0];
    float bf1 = b_ih2f[g1] + b_hh2f[g1];
    float bf2v = b_ih2f[g2];
    float bb0 = b_ih2b[g0] + b_hh2b[g0];
    float bb1 = b_ih2b[g1] + b_hh2b[g1];
    float bb2v = b_ih2b[g2];
    float af[4][3], ab[4][3];
#pragma unroll
    for (int r = 0; r < 4; ++r) {
        af[r][0] = bf0; af[r][1] = bf1; af[r][2] = bf2v;
        ab[r][0] = bb0; ab[r][1] = bb1; ab[r][2] = bb2v;
    }
#pragma unroll 4
    for (int k = 0; k < H_; ++k) {
        float wf0 = bf2f(w2ft[k * G_ + g0]);
        float wf1 = bf2f(w2ft[k * G_ + g1]);
        float wf2 = bf2f(w2ft[k * G_ + g2]);
        float wb0 = bf2f(w2bt[k * G_ + g0]);
        float wb1 = bf2f(w2bt[k * G_ + g1]);
        float wb2 = bf2f(w2bt[k * G_ + g2]);
#pragma unroll
        for (int r = 0; r < 4; ++r) {
            float mm = m[r][k];
            af[r][0] += mm * wf0; af[r][1] += mm * wf1; af[r][2] += mm * wf2;
            ab[r][0] += mm * wb0; ab[r][1] += mm * wb1; ab[r][2] += mm * wb2;
        }
    }
#pragma unroll
    for (int r = 0; r < 4; ++r) {
        xg2[0][r][g0] = af[r][0]; xg2[0][r][g1] = af[r][1]; xg2[0][r][g2] = af[r][2];
        xg2[1][r][g0] = ab[r][0]; xg2[1][r][g1] = ab[r][1]; xg2[1][r][g2] = ab[r][2];
    }
    __syncthreads();

    {
        const int j = tid;
        float bnf = b_hh2f[512 + j], bnb = b_hh2b[512 + j];
#pragma unroll
        for (int r = 0; r < 4; ++r) {
            float rg = sigm(xg2[0][r][j]);
            float zg = sigm(xg2[0][r][256 + j]);
            float ng = tanhf(xg2[0][r][512 + j] + rg * bnf);
            emb[r][j] = (1.f - zg) * ng;
            rg = sigm(xg2[1][r][j]);
            zg = sigm(xg2[1][r][256 + j]);
            ng = tanhf(xg2[1][r][512 + j] + rg * bnb);
            emb[r][256 + j] = (1.f - zg) * ng;
        }
    }
    __syncthreads();

    {
        const int o = tid;
        float acc[4];
        float b = bc1[o];
#pragma unroll
        for (int r = 0; r < 4; ++r) acc[r] = b;
#pragma unroll 4
        for (int k = 0; k < 512; ++k) {
            float w = bf2f(wc1t[k * H_ + o]);
#pragma unroll
            for (int r = 0; r < 4; ++r) acc[r] += emb[r][k] * w;
        }
#pragma unroll
        for (int r = 0; r < 4; ++r) {
            float pre = acc[r];
            hid[r][o] = pre >= 0.f ? pre : 0.1f * pre;
        }
    }
    __syncthreads();

    {
        int grp = tid >> 5, lane = tid & 31;
        int r = grp >> 1, cc = grp & 1;
        float s = 0.f;
        for (int k = lane; k < H_; k += 32) s += hid[r][k] * wc2[cc * H_ + k];
#pragma unroll
        for (int msk = 16; msk >= 1; msk >>= 1) s += __shfl_xor(s, msk, 32);
        if (lane == 0) out[(size_t)(r0 + r) * 2 + cc] = s + bc2[cc];
    }
}

// ---------------------------------------------------------------------------
extern "C" void kernel_launch(void* const* d_in, const int* in_sizes, int n_in,
                              void* d_out, int out_size, void* d_ws, size_t ws_size,
                              hipStream_t stream)
{
    const float* x      = (const float*)d_in[0];
    const float* w_ih1  = (const float*)d_in[1];
    const float* w_hh1  = (const float*)d_in[2];
    const float* b_ih1  = (const float*)d_in[3];
    const float* b_hh1  = (const float*)d_in[4];
    const float* w_ih2f = (const float*)d_in[5];
    const float* b_ih2f = (const float*)d_in[7];
    const float* b_hh2f = (const float*)d_in[8];
    const float* w_ih2b = (const float*)d_in[9];
    const float* b_ih2b = (const float*)d_in[11];
    const float* b_hh2b = (const float*)d_in[12];
    const float* wc1    = (const float*)d_in[13];
    const float* bc1    = (const float*)d_in[14];
    const float* wc2    = (const float*)d_in[15];
    const float* bc2    = (const float*)d_in[16];
    float* out = (float*)d_out;

    char* p = (char*)d_ws;
    u16* xg   = (u16*)p;  p += (size_t)M_ * G_ * 2;        // 48 MB
    u16* wihb = (u16*)p;  p += (size_t)G_ * KP_ * 2;       // 480 KB
    u16* whpk = (u16*)p;  p += (size_t)48 * 8 * 64 * 8 * 2; // 384 KB
    u16* w2ft = (u16*)p;  p += (size_t)G_ * H_ * 2;
    u16* w2bt = (u16*)p;  p += (size_t)G_ * H_ * 2;
    u16* wc1t = (u16*)p;  p += (size_t)512 * 256 * 2;
    float* mid = (float*)p; p += (size_t)NROW * H_ * 4;

    k0_prep<<<dim3(960, 5), 256, 0, stream>>>(w_ih1, w_hh1, w_ih2f, w_ih2b, wc1,
                                              wihb, whpk, w2ft, w2bt, wc1t);
    k1_xgemm<<<dim3(M_ / 128, G_ / 128), 256, 0, stream>>>(x, wihb, b_ih1, xg);
    const int k2_lds = (48 * 2 * 64 * 8 + 16 * 264) * 2;   // 106752 B
    k2_gru<<<32, 1024, k2_lds, stream>>>(xg, whpk, b_hh1, mid);
    k3_head<<<128, 256, 0, stream>>>(mid, w2ft, w2bt, b_ih2f, b_hh2f,
                                     b_ih2b, b_hh2b, wc1t, bc1, wc2, bc2, out);
}

// Round 5
// 276.450 us; speedup vs baseline: 3.5803x; 1.3887x over previous
//
#include <hip/hip_runtime.h>
#include <hip/hip_bf16.h>

typedef unsigned short u16;
typedef unsigned int u32;
using short8 = __attribute__((ext_vector_type(8))) short;
using f32x4  = __attribute__((ext_vector_type(4))) float;

#define T_   64
#define D_   300
#define H_   256
#define G_   768            // 3H
#define NROW 512            // useful sequences (s==2)
#define M_   (NROW * T_)    // 32768
#define KP_  320            // K=300 padded to 320 for MFMA

__device__ __forceinline__ float bf2f(u16 v) {
    union { u32 u; float f; } x; x.u = ((u32)v) << 16; return x.f;
}
__device__ __forceinline__ u16 f2bf(float f) {
    union { u32 u; float f; } x; x.f = f;
    u32 u = x.u;
    u32 r = (u + 0x7FFFu + ((u >> 16) & 1u)) >> 16;   // RNE
    return (u16)r;
}
__device__ __forceinline__ float frcp(float x) {
    float r; asm("v_rcp_f32 %0, %1" : "=v"(r) : "v"(x)); return r;
}
__device__ __forceinline__ float fsigm(float x) { return frcp(1.f + __expf(-x)); }
__device__ __forceinline__ float ftanh(float x) {
    return 1.f - 2.f * frcp(1.f + __expf(2.f * x));
}
__device__ __forceinline__ float sigm(float x) { return 1.f / (1.f + expf(-x)); }

// ---------------------------------------------------------------------------
// KX: cast x[:,2] (f32) -> xb [32768][320] bf16, zero-padded k>=300.
// ---------------------------------------------------------------------------
__global__ __launch_bounds__(256) void kx_cast(
    const float* __restrict__ x, u16* __restrict__ xb)
{
    const int gid = blockIdx.x * 256 + threadIdx.x;   // 32768*40 threads
    const int row = gid / 40, seg = gid - row * 40;
    const int k0 = seg * 8;
    const int n = row >> 6, t = row & 63;
    const float* src = x + (size_t)(n * 256 + 128 + t) * D_;
    union { u16 h[8]; uint4 q; } u;
    if (k0 + 8 <= D_) {
        const float4 a = *reinterpret_cast<const float4*>(src + k0);
        const float4 b = *reinterpret_cast<const float4*>(src + k0 + 4);
        u.h[0] = f2bf(a.x); u.h[1] = f2bf(a.y); u.h[2] = f2bf(a.z); u.h[3] = f2bf(a.w);
        u.h[4] = f2bf(b.x); u.h[5] = f2bf(b.y); u.h[6] = f2bf(b.z); u.h[7] = f2bf(b.w);
    } else {
#pragma unroll
        for (int e = 0; e < 8; ++e)
            u.h[e] = (k0 + e < D_) ? f2bf(src[k0 + e]) : (u16)0;
    }
    *reinterpret_cast<uint4*>(&xb[(size_t)row * KP_ + k0]) = u.q;
}

// ---------------------------------------------------------------------------
// K0: weight prep. (unchanged structure)
// ---------------------------------------------------------------------------
__global__ __launch_bounds__(256) void k0_prep(
    const float* __restrict__ w_ih1, const float* __restrict__ w_hh1,
    const float* __restrict__ w2f, const float* __restrict__ w2b,
    const float* __restrict__ wc1,
    u16* __restrict__ wihb, u16* __restrict__ whpk,
    u16* __restrict__ w2ft, u16* __restrict__ w2bt, u16* __restrict__ wc1t)
{
    int y = blockIdx.y;
    int tid = blockIdx.x * 256 + threadIdx.x;
    if (y == 0) {
        if (tid < G_ * KP_) {
            int g = tid / KP_, k = tid % KP_;
            wihb[tid] = (k < D_) ? f2bf(w_ih1[g * D_ + k]) : (u16)0;
        }
    } else if (y == 1) {
        if (tid < 48 * 8 * 64) {
            int lane = tid & 63;
            int ks = (tid >> 6) & 7;
            int nt = tid >> 9;
            int g  = nt * 16 + (lane & 15);
            int kb = ks * 32 + ((lane >> 4) << 3);
            union { u16 h[8]; uint4 q; } u;
#pragma unroll
            for (int e = 0; e < 8; ++e) u.h[e] = f2bf(w_hh1[g * H_ + kb + e]);
            *reinterpret_cast<uint4*>(&whpk[(size_t)tid * 8]) = u.q;
        }
    } else if (y == 2 || y == 3) {
        if (tid < G_ * H_) {
            int k = tid / G_, g = tid % G_;
            const float* src = (y == 2) ? w2f : w2b;
            u16* dst = (y == 2) ? w2ft : w2bt;
            dst[tid] = f2bf(src[g * H_ + k]);
        }
    } else {
        if (tid < 512 * 256) {
            int k = tid / 256, o = tid % 256;
            wc1t[tid] = f2bf(wc1[o * 512 + k]);
        }
    }
}

// ---------------------------------------------------------------------------
// K1: xg[t][n][col] = (xb @ wihb^T + b_ih1), bf16 MFMA, 128x128 tile.
// ---------------------------------------------------------------------------
__global__ __launch_bounds__(256) void k1_xgemm(
    const u16* __restrict__ xb, const u16* __restrict__ wihb,
    const float* __restrict__ bih, u16* __restrict__ xg)
{
    __shared__ alignas(16) u16 As[128 * 40];
    __shared__ alignas(16) u16 Bs[128 * 40];
    const int tid = threadIdx.x;
    const int l = tid & 63, wv = tid >> 6;
    const int wrow = wv >> 1, wcol = wv & 1;
    const int row0 = blockIdx.x * 128, col0 = blockIdx.y * 128;

    f32x4 acc[4][4];
#pragma unroll
    for (int i = 0; i < 4; ++i)
#pragma unroll
        for (int j = 0; j < 4; ++j) acc[i][j] = (f32x4){0.f, 0.f, 0.f, 0.f};

    const int ar = tid >> 1, ah = tid & 1;
    const u16* xrow  = xb + (size_t)(row0 + ar) * KP_;
    const u16* wrowp = wihb + (size_t)(col0 + ar) * KP_;

    for (int k0 = 0; k0 < KP_; k0 += 32) {
        *reinterpret_cast<uint4*>(&As[ar * 40 + ah * 16]) =
            *reinterpret_cast<const uint4*>(xrow + k0 + ah * 16);
        *reinterpret_cast<uint4*>(&As[ar * 40 + ah * 16 + 8]) =
            *reinterpret_cast<const uint4*>(xrow + k0 + ah * 16 + 8);
        *reinterpret_cast<uint4*>(&Bs[ar * 40 + ah * 16]) =
            *reinterpret_cast<const uint4*>(wrowp + k0 + ah * 16);
        *reinterpret_cast<uint4*>(&Bs[ar * 40 + ah * 16 + 8]) =
            *reinterpret_cast<const uint4*>(wrowp + k0 + ah * 16 + 8);
        __syncthreads();

        short8 af[4], bf[4];
#pragma unroll
        for (int fi = 0; fi < 4; ++fi)
            af[fi] = *reinterpret_cast<const short8*>(
                &As[(wrow * 64 + fi * 16 + (l & 15)) * 40 + ((l >> 4) << 3)]);
#pragma unroll
        for (int fj = 0; fj < 4; ++fj)
            bf[fj] = *reinterpret_cast<const short8*>(
                &Bs[(wcol * 64 + fj * 16 + (l & 15)) * 40 + ((l >> 4) << 3)]);
#pragma unroll
        for (int fi = 0; fi < 4; ++fi)
#pragma unroll
            for (int fj = 0; fj < 4; ++fj)
                acc[fi][fj] = __builtin_amdgcn_mfma_f32_16x16x32_bf16(
                    af[fi], bf[fj], acc[fi][fj], 0, 0, 0);
        __syncthreads();
    }

    float bias[4];
#pragma unroll
    for (int fj = 0; fj < 4; ++fj)
        bias[fj] = bih[col0 + wcol * 64 + fj * 16 + (l & 15)];
#pragma unroll
    for (int fi = 0; fi < 4; ++fi)
#pragma unroll
        for (int fj = 0; fj < 4; ++fj)
#pragma unroll
            for (int q = 0; q < 4; ++q) {
                int row = row0 + wrow * 64 + fi * 16 + ((l >> 4) << 2) + q;
                int col = col0 + wcol * 64 + fj * 16 + (l & 15);
                // layout: [t][n][G]
                xg[((size_t)(row & 63) * NROW + (row >> 6)) * G_ + col] =
                    f2bf(acc[fi][fj][q] + bias[fj]);
            }
}

// ---------------------------------------------------------------------------
// K2 v3: 32 blocks x 512 thr (8 waves, 2 waves/EU forced -> 256 VGPR budget).
// Wave w owns units [32w,32w+32) for all 3 gates (6 tiles). Weights:
// ks0-5 in regs (144 VGPR), ks6-7 in LDS (98 KB). h master in regs.
// Raw s_barrier + lgkmcnt(0); xv loaded at step top, consumed after B1.
// ---------------------------------------------------------------------------
__device__ __forceinline__ void gru_stepA(
    const u16* __restrict__ xg, const u16* wl, u16* hb,
    const short8 (&wreg)[6][6], const u32 (&xo)[2][4], const float (&bh)[3][2],
    float (&h)[2][4], int t, int l, int wv, int rgrp)
{
    const int arow = l & 15;
    const int klo  = (l >> 4) << 3;

    // issue this step's xg loads (h-independent; cover = MFMA phase + B1)
    u32 xv[3][2][4];
    const u16* xt = xg + (size_t)t * ((size_t)NROW * G_);
#pragma unroll
    for (int a = 0; a < 2; ++a)
#pragma unroll
        for (int q = 0; q < 4; ++q) {
            xv[0][a][q] = xt[xo[a][q]];
            xv[1][a][q] = xt[xo[a][q] + 256];
            xv[2][a][q] = xt[xo[a][q] + 512];
        }

    // MFMA phase: hg = h @ W for this wave's 6 tiles
    f32x4 acc[6];
#pragma unroll
    for (int m = 0; m < 6; ++m) acc[m] = (f32x4){0.f, 0.f, 0.f, 0.f};
    __builtin_amdgcn_s_setprio(1);
#pragma unroll
    for (int ks = 0; ks < 8; ++ks) {
        const short8 afr = *reinterpret_cast<const short8*>(
            &hb[arow * 264 + ks * 32 + klo]);
        if (ks < 6) {
#pragma unroll
            for (int m = 0; m < 6; ++m)
                acc[m] = __builtin_amdgcn_mfma_f32_16x16x32_bf16(
                    afr, wreg[m][ks], acc[m], 0, 0, 0);
        } else {
#pragma unroll
            for (int gt = 0; gt < 3; ++gt)
#pragma unroll
                for (int a = 0; a < 2; ++a) {
                    const int nt2 = (gt * 16 + wv * 2 + a) * 2 + (ks - 6);
                    const short8 bfr = *reinterpret_cast<const short8*>(
                        &wl[(size_t)(nt2 * 64 + l) * 8]);
                    acc[gt * 2 + a] = __builtin_amdgcn_mfma_f32_16x16x32_bf16(
                        afr, bfr, acc[gt * 2 + a], 0, 0, 0);
                }
        }
    }
    __builtin_amdgcn_s_setprio(0);

    // B1: all waves done READING hb (lgkm only; globals stay in flight)
    asm volatile("s_waitcnt lgkmcnt(0)" ::: "memory");
    __builtin_amdgcn_sched_barrier(0);
    __builtin_amdgcn_s_barrier();
    __builtin_amdgcn_sched_barrier(0);

    // update phase (wave-local): 8 (row,unit) pairs per lane
#pragma unroll
    for (int a = 0; a < 2; ++a)
#pragma unroll
        for (int q = 0; q < 4; ++q) {
            const float xr = bf2f((u16)xv[0][a][q]);
            const float xz = bf2f((u16)xv[1][a][q]);
            const float xn = bf2f((u16)xv[2][a][q]);
            const float rg = fsigm(xr + acc[0 + a][q] + bh[0][a]);
            const float zg = fsigm(xz + acc[2 + a][q] + bh[1][a]);
            const float ng = ftanh(xn + rg * (acc[4 + a][q] + bh[2][a]));
            h[a][q] = zg * (h[a][q] - ng) + ng;
            hb[(rgrp * 4 + q) * 264 + wv * 32 + a * 16 + (l & 15)] = f2bf(h[a][q]);
        }

    // B2: writes visible before next step's reads
    asm volatile("s_waitcnt lgkmcnt(0)" ::: "memory");
    __builtin_amdgcn_sched_barrier(0);
    __builtin_amdgcn_s_barrier();
    __builtin_amdgcn_sched_barrier(0);
}

__global__ __launch_bounds__(512)
__attribute__((amdgpu_waves_per_eu(2, 2)))
void k2_gru(const u16* __restrict__ xg, const u16* __restrict__ whpk,
            const float* __restrict__ b_hh, float* __restrict__ mid)
{
    extern __shared__ u16 smem[];
    u16* wl = smem;                        // 48*2*64*8 u16 = 98304 B
    u16* hb = smem + 48 * 2 * 64 * 8;      // 16*264 u16 = 8448 B
    const int tid = threadIdx.x;
    const int l = tid & 63, wv = tid >> 6;   // wv in [0,8)
    const int n0 = blockIdx.x * 16;
    const int col = l & 15, rgrp = l >> 4;

    // persistent weights ks 0..5 (144 VGPR): tile m = gt*2+a
    short8 wreg[6][6];
#pragma unroll
    for (int gt = 0; gt < 3; ++gt)
#pragma unroll
        for (int a = 0; a < 2; ++a) {
            const int nt = gt * 16 + wv * 2 + a;
#pragma unroll
            for (int ks = 0; ks < 6; ++ks)
                wreg[gt * 2 + a][ks] = *reinterpret_cast<const short8*>(
                    &whpk[(size_t)((nt * 8 + ks) * 64 + l) * 8]);
        }
    // stage ks 6..7 into LDS
    for (int c = tid; c < 48 * 2 * 64; c += 512) {
        const int nt = c >> 7, j = (c >> 6) & 1, ll = c & 63;
        *reinterpret_cast<uint4*>(&wl[(size_t)c * 8]) =
            *reinterpret_cast<const uint4*>(
                &whpk[(size_t)((nt * 8 + 6 + j) * 64 + ll) * 8]);
    }
    for (int i = tid; i < 16 * 264 / 2; i += 512) ((u32*)hb)[i] = 0;

    float bh[3][2];
    u32 xo[2][4];
#pragma unroll
    for (int a = 0; a < 2; ++a) {
        const int ju = wv * 32 + a * 16 + col;
        bh[0][a] = b_hh[ju];
        bh[1][a] = b_hh[256 + ju];
        bh[2][a] = b_hh[512 + ju];
#pragma unroll
        for (int q = 0; q < 4; ++q)
            xo[a][q] = (u32)(n0 + rgrp * 4 + q) * G_ + ju;
    }
    float h[2][4] = {};

    __syncthreads();

    for (int t = 0; t < T_; ++t)
        gru_stepA(xg, wl, hb, wreg, xo, bh, h, t, l, wv, rgrp);

#pragma unroll
    for (int a = 0; a < 2; ++a)
#pragma unroll
        for (int q = 0; q < 4; ++q)
            mid[(size_t)(n0 + rgrp * 4 + q) * H_ + wv * 32 + a * 16 + col] = h[a][q];
}

// ---------------------------------------------------------------------------
// K3: head. (unchanged)
// ---------------------------------------------------------------------------
__global__ __launch_bounds__(256) void k3_head(
    const float* __restrict__ mid,
    const u16* __restrict__ w2ft, const u16* __restrict__ w2bt,
    const float* __restrict__ b_ih2f, const float* __restrict__ b_hh2f,
    const float* __restrict__ b_ih2b, const float* __restrict__ b_hh2b,
    const u16* __restrict__ wc1t, const float* __restrict__ bc1,
    const float* __restrict__ wc2, const float* __restrict__ bc2,
    float* __restrict__ out)
{
    __shared__ float m[4][H_];
    __shared__ float xg2[2][4][G_];
    __shared__ float emb[4][512];
    __shared__ float hid[4][H_];
    int tid = threadIdx.x;
    int r0 = blockIdx.x * 4;

    for (int i = tid; i < 4 * H_; i += 256) {
        int r = i >> 8, k = i & 255;
        m[r][k] = mid[(size_t)(r0 + r) * H_ + k];
    }
    __syncthreads();

    const int g0 = tid, g1 = tid + 256, g2 = tid + 512;
    float bf0 = b_ih2f[g0] + b_hh2f[g0];
    float bf1 = b_ih2f[g1] + b_hh2f[g1];
    float bf2v = b_ih2f[g2];
    float bb0 = b_ih2b[g0] + b_hh2b[g0];
    float bb1 = b_ih2b[g1] + b_hh2b[g1];
    float bb2v = b_ih2b[g2];
    float af[4][3], ab[4][3];
#pragma unroll
    for (int r = 0; r < 4; ++r) {
        af[r][0] = bf0; af[r][1] = bf1; af[r][2] = bf2v;
        ab[r][0] = bb0; ab[r][1] = bb1; ab[r][2] = bb2v;
    }
#pragma unroll 4
    for (int k = 0; k < H_; ++k) {
        float wf0 = bf2f(w2ft[k * G_ + g0]);
        float wf1 = bf2f(w2ft[k * G_ + g1]);
        float wf2 = bf2f(w2ft[k * G_ + g2]);
        float wb0 = bf2f(w2bt[k * G_ + g0]);
        float wb1 = bf2f(w2bt[k * G_ + g1]);
        float wb2 = bf2f(w2bt[k * G_ + g2]);
#pragma unroll
        for (int r = 0; r < 4; ++r) {
            float mm = m[r][k];
            af[r][0] += mm * wf0; af[r][1] += mm * wf1; af[r][2] += mm * wf2;
            ab[r][0] += mm * wb0; ab[r][1] += mm * wb1; ab[r][2] += mm * wb2;
        }
    }
#pragma unroll
    for (int r = 0; r < 4; ++r) {
        xg2[0][r][g0] = af[r][0]; xg2[0][r][g1] = af[r][1]; xg2[0][r][g2] = af[r][2];
        xg2[1][r][g0] = ab[r][0]; xg2[1][r][g1] = ab[r][1]; xg2[1][r][g2] = ab[r][2];
    }
    __syncthreads();

    {
        const int j = tid;
        float bnf = b_hh2f[512 + j], bnb = b_hh2b[512 + j];
#pragma unroll
        for (int r = 0; r < 4; ++r) {
            float rg = sigm(xg2[0][r][j]);
            float zg = sigm(xg2[0][r][256 + j]);
            float ng = tanhf(xg2[0][r][512 + j] + rg * bnf);
            emb[r][j] = (1.f - zg) * ng;
            rg = sigm(xg2[1][r][j]);
            zg = sigm(xg2[1][r][256 + j]);
            ng = tanhf(xg2[1][r][512 + j] + rg * bnb);
            emb[r][256 + j] = (1.f - zg) * ng;
        }
    }
    __syncthreads();

    {
        const int o = tid;
        float acc[4];
        float b = bc1[o];
#pragma unroll
        for (int r = 0; r < 4; ++r) acc[r] = b;
#pragma unroll 4
        for (int k = 0; k < 512; ++k) {
            float w = bf2f(wc1t[k * H_ + o]);
#pragma unroll
            for (int r = 0; r < 4; ++r) acc[r] += emb[r][k] * w;
        }
#pragma unroll
        for (int r = 0; r < 4; ++r) {
            float pre = acc[r];
            hid[r][o] = pre >= 0.f ? pre : 0.1f * pre;
        }
    }
    __syncthreads();

    {
        int grp = tid >> 5, lane = tid & 31;
        int r = grp >> 1, cc = grp & 1;
        float s = 0.f;
        for (int k = lane; k < H_; k += 32) s += hid[r][k] * wc2[cc * H_ + k];
#pragma unroll
        for (int msk = 16; msk >= 1; msk >>= 1) s += __shfl_xor(s, msk, 32);
        if (lane == 0) out[(size_t)(r0 + r) * 2 + cc] = s + bc2[cc];
    }
}

// ---------------------------------------------------------------------------
extern "C" void kernel_launch(void* const* d_in, const int* in_sizes, int n_in,
                              void* d_out, int out_size, void* d_ws, size_t ws_size,
                              hipStream_t stream)
{
    const float* x      = (const float*)d_in[0];
    const float* w_ih1  = (const float*)d_in[1];
    const float* w_hh1  = (const float*)d_in[2];
    const float* b_ih1  = (const float*)d_in[3];
    const float* b_hh1  = (const float*)d_in[4];
    const float* w_ih2f = (const float*)d_in[5];
    const float* b_ih2f = (const float*)d_in[7];
    const float* b_hh2f = (const float*)d_in[8];
    const float* w_ih2b = (const float*)d_in[9];
    const float* b_ih2b = (const float*)d_in[11];
    const float* b_hh2b = (const float*)d_in[12];
    const float* wc1    = (const float*)d_in[13];
    const float* bc1    = (const float*)d_in[14];
    const float* wc2    = (const float*)d_in[15];
    const float* bc2    = (const float*)d_in[16];
    float* out = (float*)d_out;

    char* p = (char*)d_ws;
    u16* xg   = (u16*)p;  p += (size_t)M_ * G_ * 2;          // 48 MB, [t][n][G]
    u16* xb   = (u16*)p;  p += (size_t)M_ * KP_ * 2;         // 20 MB
    u16* wihb = (u16*)p;  p += (size_t)G_ * KP_ * 2;         // 480 KB
    u16* whpk = (u16*)p;  p += (size_t)48 * 8 * 64 * 8 * 2;  // 384 KB
    u16* w2ft = (u16*)p;  p += (size_t)G_ * H_ * 2;
    u16* w2bt = (u16*)p;  p += (size_t)G_ * H_ * 2;
    u16* wc1t = (u16*)p;  p += (size_t)512 * 256 * 2;
    float* mid = (float*)p; p += (size_t)NROW * H_ * 4;

    kx_cast<<<M_ * 40 / 256, 256, 0, stream>>>(x, xb);
    k0_prep<<<dim3(960, 5), 256, 0, stream>>>(w_ih1, w_hh1, w_ih2f, w_ih2b, wc1,
                                              wihb, whpk, w2ft, w2bt, wc1t);
    k1_xgemm<<<dim3(M_ / 128, G_ / 128), 256, 0, stream>>>(xb, wihb, b_ih1, xg);
    const int k2_lds = (48 * 2 * 64 * 8 + 16 * 264) * 2;   // 106752 B
    k2_gru<<<32, 512, k2_lds, stream>>>(xg, whpk, b_hh1, mid);
    k3_head<<<128, 256, 0, stream>>>(mid, w2ft, w2bt, b_ih2f, b_hh2f,
                                     b_ih2b, b_hh2b, wc1t, bc1, wc2, bc2, out);
}

// Round 6
// 269.762 us; speedup vs baseline: 3.6690x; 1.0248x over previous
//
#include <hip/hip_runtime.h>
#include <hip/hip_bf16.h>

typedef unsigned short u16;
typedef unsigned int u32;
using short8 = __attribute__((ext_vector_type(8))) short;
using f32x4  = __attribute__((ext_vector_type(4))) float;

#define T_   64
#define D_   300
#define H_   256
#define G_   768            // 3H
#define NROW 512            // useful sequences (s==2)
#define M_   (NROW * T_)    // 32768
#define KP_  320            // K=300 padded to 320 for MFMA

__device__ __forceinline__ float bf2f(u16 v) {
    union { u32 u; float f; } x; x.u = ((u32)v) << 16; return x.f;
}
__device__ __forceinline__ u16 f2bf(float f) {
    union { u32 u; float f; } x; x.f = f;
    u32 u = x.u;
    u32 r = (u + 0x7FFFu + ((u >> 16) & 1u)) >> 16;   // RNE
    return (u16)r;
}
__device__ __forceinline__ float frcp(float x) {
    float r; asm("v_rcp_f32 %0, %1" : "=v"(r) : "v"(x)); return r;
}
__device__ __forceinline__ float fsigm(float x) { return frcp(1.f + __expf(-x)); }
__device__ __forceinline__ float ftanh(float x) {
    return 1.f - 2.f * frcp(1.f + __expf(2.f * x));
}
__device__ __forceinline__ float sigm(float x) { return 1.f / (1.f + expf(-x)); }

// ---------------------------------------------------------------------------
// KX: cast x[:,2] (f32) -> xb [32768][320] bf16, zero-padded k>=300.
// ---------------------------------------------------------------------------
__global__ __launch_bounds__(256) void kx_cast(
    const float* __restrict__ x, u16* __restrict__ xb)
{
    const int gid = blockIdx.x * 256 + threadIdx.x;   // 32768*40 threads
    const int row = gid / 40, seg = gid - row * 40;
    const int k0 = seg * 8;
    const int n = row >> 6, t = row & 63;
    const float* src = x + (size_t)(n * 256 + 128 + t) * D_;
    union { u16 h[8]; uint4 q; } u;
    if (k0 + 8 <= D_) {
        const float4 a = *reinterpret_cast<const float4*>(src + k0);
        const float4 b = *reinterpret_cast<const float4*>(src + k0 + 4);
        u.h[0] = f2bf(a.x); u.h[1] = f2bf(a.y); u.h[2] = f2bf(a.z); u.h[3] = f2bf(a.w);
        u.h[4] = f2bf(b.x); u.h[5] = f2bf(b.y); u.h[6] = f2bf(b.z); u.h[7] = f2bf(b.w);
    } else {
#pragma unroll
        for (int e = 0; e < 8; ++e)
            u.h[e] = (k0 + e < D_) ? f2bf(src[k0 + e]) : (u16)0;
    }
    *reinterpret_cast<uint4*>(&xb[(size_t)row * KP_ + k0]) = u.q;
}

// ---------------------------------------------------------------------------
// K0: weight prep + combined bias.
//  biasc[g] = b_ih1[g] + (g<512 ? b_hh1[g] : 0)   (r,z folded; n keeps b_ih)
// ---------------------------------------------------------------------------
__global__ __launch_bounds__(256) void k0_prep(
    const float* __restrict__ w_ih1, const float* __restrict__ w_hh1,
    const float* __restrict__ b_ih1, const float* __restrict__ b_hh1,
    const float* __restrict__ w2f, const float* __restrict__ w2b,
    const float* __restrict__ wc1,
    u16* __restrict__ wihb, u16* __restrict__ whpk,
    u16* __restrict__ w2ft, u16* __restrict__ w2bt, u16* __restrict__ wc1t,
    float* __restrict__ biasc)
{
    int y = blockIdx.y;
    int tid = blockIdx.x * 256 + threadIdx.x;
    if (y == 0) {
        if (tid < G_ * KP_) {
            int g = tid / KP_, k = tid % KP_;
            wihb[tid] = (k < D_) ? f2bf(w_ih1[g * D_ + k]) : (u16)0;
        }
    } else if (y == 1) {
        if (tid < 48 * 8 * 64) {
            int lane = tid & 63;
            int ks = (tid >> 6) & 7;
            int nt = tid >> 9;
            int g  = nt * 16 + (lane & 15);
            int kb = ks * 32 + ((lane >> 4) << 3);
            union { u16 h[8]; uint4 q; } u;
#pragma unroll
            for (int e = 0; e < 8; ++e) u.h[e] = f2bf(w_hh1[g * H_ + kb + e]);
            *reinterpret_cast<uint4*>(&whpk[(size_t)tid * 8]) = u.q;
        }
    } else if (y == 2 || y == 3) {
        if (tid < G_ * H_) {
            int k = tid / G_, g = tid % G_;
            const float* src = (y == 2) ? w2f : w2b;
            u16* dst = (y == 2) ? w2ft : w2bt;
            dst[tid] = f2bf(src[g * H_ + k]);
        }
    } else {
        if (tid < 512 * 256) {
            int k = tid / 256, o = tid % 256;
            wc1t[tid] = f2bf(wc1[o * 512 + k]);
        }
        if (tid < G_)
            biasc[tid] = b_ih1[tid] + (tid < 2 * H_ ? b_hh1[tid] : 0.f);
    }
}

// ---------------------------------------------------------------------------
// K1: xg[t][n][col] = (xb @ wihb^T + biasc), bf16 MFMA, 128x128 tile.
// ---------------------------------------------------------------------------
__global__ __launch_bounds__(256) void k1_xgemm(
    const u16* __restrict__ xb, const u16* __restrict__ wihb,
    const float* __restrict__ biasc, u16* __restrict__ xg)
{
    __shared__ alignas(16) u16 As[128 * 40];
    __shared__ alignas(16) u16 Bs[128 * 40];
    const int tid = threadIdx.x;
    const int l = tid & 63, wv = tid >> 6;
    const int wrow = wv >> 1, wcol = wv & 1;
    const int row0 = blockIdx.x * 128, col0 = blockIdx.y * 128;

    f32x4 acc[4][4];
#pragma unroll
    for (int i = 0; i < 4; ++i)
#pragma unroll
        for (int j = 0; j < 4; ++j) acc[i][j] = (f32x4){0.f, 0.f, 0.f, 0.f};

    const int ar = tid >> 1, ah = tid & 1;
    const u16* xrow  = xb + (size_t)(row0 + ar) * KP_;
    const u16* wrowp = wihb + (size_t)(col0 + ar) * KP_;

    for (int k0 = 0; k0 < KP_; k0 += 32) {
        *reinterpret_cast<uint4*>(&As[ar * 40 + ah * 16]) =
            *reinterpret_cast<const uint4*>(xrow + k0 + ah * 16);
        *reinterpret_cast<uint4*>(&As[ar * 40 + ah * 16 + 8]) =
            *reinterpret_cast<const uint4*>(xrow + k0 + ah * 16 + 8);
        *reinterpret_cast<uint4*>(&Bs[ar * 40 + ah * 16]) =
            *reinterpret_cast<const uint4*>(wrowp + k0 + ah * 16);
        *reinterpret_cast<uint4*>(&Bs[ar * 40 + ah * 16 + 8]) =
            *reinterpret_cast<const uint4*>(wrowp + k0 + ah * 16 + 8);
        __syncthreads();

        short8 af[4], bf[4];
#pragma unroll
        for (int fi = 0; fi < 4; ++fi)
            af[fi] = *reinterpret_cast<const short8*>(
                &As[(wrow * 64 + fi * 16 + (l & 15)) * 40 + ((l >> 4) << 3)]);
#pragma unroll
        for (int fj = 0; fj < 4; ++fj)
            bf[fj] = *reinterpret_cast<const short8*>(
                &Bs[(wcol * 64 + fj * 16 + (l & 15)) * 40 + ((l >> 4) << 3)]);
#pragma unroll
        for (int fi = 0; fi < 4; ++fi)
#pragma unroll
            for (int fj = 0; fj < 4; ++fj)
                acc[fi][fj] = __builtin_amdgcn_mfma_f32_16x16x32_bf16(
                    af[fi], bf[fj], acc[fi][fj], 0, 0, 0);
        __syncthreads();
    }

    float bias[4];
#pragma unroll
    for (int fj = 0; fj < 4; ++fj)
        bias[fj] = biasc[col0 + wcol * 64 + fj * 16 + (l & 15)];
#pragma unroll
    for (int fi = 0; fi < 4; ++fi)
#pragma unroll
        for (int fj = 0; fj < 4; ++fj)
#pragma unroll
            for (int q = 0; q < 4; ++q) {
                int row = row0 + wrow * 64 + fi * 16 + ((l >> 4) << 2) + q;
                int col = col0 + wcol * 64 + fj * 16 + (l & 15);
                // layout: [t][n][G]
                xg[((size_t)(row & 63) * NROW + (row >> 6)) * G_ + col] =
                    f2bf(acc[fi][fj][q] + bias[fj]);
            }
}

// ---------------------------------------------------------------------------
// K2 v4: 32 blocks x 512 thr. Weights ks0-5 PINNED in VGPRs via asm "+v"
// (rematerialization now illegal); ks6-7 in LDS. 2 waves/EU -> 256 VGPR cap.
// ---------------------------------------------------------------------------
#define PIN_W asm volatile("" : \
    "+v"(wr[0][0]),"+v"(wr[0][1]),"+v"(wr[0][2]),"+v"(wr[0][3]),"+v"(wr[0][4]),"+v"(wr[0][5]), \
    "+v"(wr[1][0]),"+v"(wr[1][1]),"+v"(wr[1][2]),"+v"(wr[1][3]),"+v"(wr[1][4]),"+v"(wr[1][5]), \
    "+v"(wr[2][0]),"+v"(wr[2][1]),"+v"(wr[2][2]),"+v"(wr[2][3]),"+v"(wr[2][4]),"+v"(wr[2][5]), \
    "+v"(wr[3][0]),"+v"(wr[3][1]),"+v"(wr[3][2]),"+v"(wr[3][3]),"+v"(wr[3][4]),"+v"(wr[3][5]), \
    "+v"(wr[4][0]),"+v"(wr[4][1]),"+v"(wr[4][2]),"+v"(wr[4][3]),"+v"(wr[4][4]),"+v"(wr[4][5]), \
    "+v"(wr[5][0]),"+v"(wr[5][1]),"+v"(wr[5][2]),"+v"(wr[5][3]),"+v"(wr[5][4]),"+v"(wr[5][5]))

__global__ __launch_bounds__(512)
__attribute__((amdgpu_waves_per_eu(2, 2)))
void k2_gru(const u16* __restrict__ xg, const u16* __restrict__ whpk,
            const float* __restrict__ b_hh, float* __restrict__ mid)
{
    extern __shared__ u16 smem[];
    u16* wl = smem;                        // ks6-7: 48*2*64*8 u16 = 98304 B
    u16* hb = smem + 48 * 2 * 64 * 8;      // 16*264 u16 = 8448 B
    const int tid = threadIdx.x;
    const int l = tid & 63, wv = tid >> 6;   // wv in [0,8)
    const int n0 = blockIdx.x * 16;
    const int col = l & 15, rgrp = l >> 4;
    const int arow = col, klo = rgrp << 3;

    // persistent weights ks 0..5 (144 VGPR): tile m = gt*2+a
    short8 wr[6][6];
#pragma unroll
    for (int gt = 0; gt < 3; ++gt)
#pragma unroll
        for (int a = 0; a < 2; ++a) {
            const int nt = gt * 16 + wv * 2 + a;
#pragma unroll
            for (int ks = 0; ks < 6; ++ks)
                wr[gt * 2 + a][ks] = *reinterpret_cast<const short8*>(
                    &whpk[(size_t)((nt * 8 + ks) * 64 + l) * 8]);
        }
    // stage ks 6..7 into LDS
    for (int c = tid; c < 48 * 2 * 64; c += 512) {
        const int nt = c >> 7, j = (c >> 6) & 1, ll = c & 63;
        *reinterpret_cast<uint4*>(&wl[(size_t)c * 8]) =
            *reinterpret_cast<const uint4*>(
                &whpk[(size_t)((nt * 8 + 6 + j) * 64 + ll) * 8]);
    }
    for (int i = tid; i < 16 * 264 / 2; i += 512) ((u32*)hb)[i] = 0;

    float bhn[2];
    u32 xo[2][4];
#pragma unroll
    for (int a = 0; a < 2; ++a) {
        const int ju = wv * 32 + a * 16 + col;
        bhn[a] = b_hh[512 + ju];
#pragma unroll
        for (int q = 0; q < 4; ++q)
            xo[a][q] = (u32)(rgrp * 4 + q) * G_ + ju;
    }
    float h[2][4] = {};
    const u16* xgn = xg + (size_t)n0 * G_;

    __syncthreads();

    for (int t = 0; t < T_; ++t) {
        PIN_W;   // forbid rematerialization of wr across iterations

        // issue this step's xg loads (h-independent; cover = MFMA phase + B1)
        u32 xv[3][2][4];
        const u16* xt = xgn + (size_t)t * ((size_t)NROW * G_);
#pragma unroll
        for (int a = 0; a < 2; ++a)
#pragma unroll
            for (int q = 0; q < 4; ++q) {
                xv[0][a][q] = xt[xo[a][q]];
                xv[1][a][q] = xt[xo[a][q] + 256];
                xv[2][a][q] = xt[xo[a][q] + 512];
            }

        // MFMA phase: hg = h @ W for this wave's 6 tiles
        f32x4 acc[6];
#pragma unroll
        for (int m = 0; m < 6; ++m) acc[m] = (f32x4){0.f, 0.f, 0.f, 0.f};
        __builtin_amdgcn_s_setprio(1);
#pragma unroll
        for (int ks = 0; ks < 6; ++ks) {
            const short8 afr = *reinterpret_cast<const short8*>(
                &hb[arow * 264 + ks * 32 + klo]);
#pragma unroll
            for (int m = 0; m < 6; ++m)
                acc[m] = __builtin_amdgcn_mfma_f32_16x16x32_bf16(
                    afr, wr[m][ks], acc[m], 0, 0, 0);
        }
#pragma unroll
        for (int ks = 6; ks < 8; ++ks) {
            const short8 afr = *reinterpret_cast<const short8*>(
                &hb[arow * 264 + ks * 32 + klo]);
#pragma unroll
            for (int gt = 0; gt < 3; ++gt)
#pragma unroll
                for (int a = 0; a < 2; ++a) {
                    const int nt2 = (gt * 16 + wv * 2 + a) * 2 + (ks - 6);
                    const short8 bfr = *reinterpret_cast<const short8*>(
                        &wl[(size_t)(nt2 * 64 + l) * 8]);
                    acc[gt * 2 + a] = __builtin_amdgcn_mfma_f32_16x16x32_bf16(
                        afr, bfr, acc[gt * 2 + a], 0, 0, 0);
                }
        }
        __builtin_amdgcn_s_setprio(0);

        // B1: all waves done READING hb (lgkm only; globals stay in flight)
        asm volatile("s_waitcnt lgkmcnt(0)" ::: "memory");
        __builtin_amdgcn_sched_barrier(0);
        __builtin_amdgcn_s_barrier();
        __builtin_amdgcn_sched_barrier(0);

        // update phase (wave-local): 8 (row,unit) pairs per lane
#pragma unroll
        for (int a = 0; a < 2; ++a)
#pragma unroll
            for (int q = 0; q < 4; ++q) {
                const float xr = bf2f((u16)xv[0][a][q]);
                const float xz = bf2f((u16)xv[1][a][q]);
                const float xn = bf2f((u16)xv[2][a][q]);
                const float rg = fsigm(xr + acc[0 + a][q]);
                const float zg = fsigm(xz + acc[2 + a][q]);
                const float ng = ftanh(xn + rg * (acc[4 + a][q] + bhn[a]));
                h[a][q] = zg * (h[a][q] - ng) + ng;
                hb[(rgrp * 4 + q) * 264 + wv * 32 + a * 16 + col] = f2bf(h[a][q]);
            }

        // B2: writes visible before next step's reads
        asm volatile("s_waitcnt lgkmcnt(0)" ::: "memory");
        __builtin_amdgcn_sched_barrier(0);
        __builtin_amdgcn_s_barrier();
        __builtin_amdgcn_sched_barrier(0);
    }

#pragma unroll
    for (int a = 0; a < 2; ++a)
#pragma unroll
        for (int q = 0; q < 4; ++q)
            mid[(size_t)(n0 + rgrp * 4 + q) * H_ + wv * 32 + a * 16 + col] = h[a][q];
}

// ---------------------------------------------------------------------------
// K3: head. (unchanged)
// ---------------------------------------------------------------------------
__global__ __launch_bounds__(256) void k3_head(
    const float* __restrict__ mid,
    const u16* __restrict__ w2ft, const u16* __restrict__ w2bt,
    const float* __restrict__ b_ih2f, const float* __restrict__ b_hh2f,
    const float* __restrict__ b_ih2b, const float* __restrict__ b_hh2b,
    const u16* __restrict__ wc1t, const float* __restrict__ bc1,
    const float* __restrict__ wc2, const float* __restrict__ bc2,
    float* __restrict__ out)
{
    __shared__ float m[4][H_];
    __shared__ float xg2[2][4][G_];
    __shared__ float emb[4][512];
    __shared__ float hid[4][H_];
    int tid = threadIdx.x;
    int r0 = blockIdx.x * 4;

    for (int i = tid; i < 4 * H_; i += 256) {
        int r = i >> 8, k = i & 255;
        m[r][k] = mid[(size_t)(r0 + r) * H_ + k];
    }
    __syncthreads();

    const int g0 = tid, g1 = tid + 256, g2 = tid + 512;
    float bf0 = b_ih2f[g0] + b_hh2f[g0];
    float bf1 = b_ih2f[g1] + b_hh2f[g1];
    float bf2v = b_ih2f[g2];
    float bb0 = b_ih2b[g0] + b_hh2b[g0];
    float bb1 = b_ih2b[g1] + b_hh2b[g1];
    float bb2v = b_ih2b[g2];
    float af[4][3], ab[4][3];
#pragma unroll
    for (int r = 0; r < 4; ++r) {
        af[r][0] = bf0; af[r][1] = bf1; af[r][2] = bf2v;
        ab[r][0] = bb0; ab[r][1] = bb1; ab[r][2] = bb2v;
    }
#pragma unroll 4
    for (int k = 0; k < H_; ++k) {
        float wf0 = bf2f(w2ft[k * G_ + g0]);
        float wf1 = bf2f(w2ft[k * G_ + g1]);
        float wf2 = bf2f(w2ft[k * G_ + g2]);
        float wb0 = bf2f(w2bt[k * G_ + g0]);
        float wb1 = bf2f(w2bt[k * G_ + g1]);
        float wb2 = bf2f(w2bt[k * G_ + g2]);
#pragma unroll
        for (int r = 0; r < 4; ++r) {
            float mm = m[r][k];
            af[r][0] += mm * wf0; af[r][1] += mm * wf1; af[r][2] += mm * wf2;
            ab[r][0] += mm * wb0; ab[r][1] += mm * wb1; ab[r][2] += mm * wb2;
        }
    }
#pragma unroll
    for (int r = 0; r < 4; ++r) {
        xg2[0][r][g0] = af[r][0]; xg2[0][r][g1] = af[r][1]; xg2[0][r][g2] = af[r][2];
        xg2[1][r][g0] = ab[r][0]; xg2[1][r][g1] = ab[r][1]; xg2[1][r][g2] = ab[r][2];
    }
    __syncthreads();

    {
        const int j = tid;
        float bnf = b_hh2f[512 + j], bnb = b_hh2b[512 + j];
#pragma unroll
        for (int r = 0; r < 4; ++r) {
            float rg = sigm(xg2[0][r][j]);
            float zg = sigm(xg2[0][r][256 + j]);
            float ng = tanhf(xg2[0][r][512 + j] + rg * bnf);
            emb[r][j] = (1.f - zg) * ng;
            rg = sigm(xg2[1][r][j]);
            zg = sigm(xg2[1][r][256 + j]);
            ng = tanhf(xg2[1][r][512 + j] + rg * bnb);
            emb[r][256 + j] = (1.f - zg) * ng;
        }
    }
    __syncthreads();

    {
        const int o = tid;
        float acc[4];
        float b = bc1[o];
#pragma unroll
        for (int r = 0; r < 4; ++r) acc[r] = b;
#pragma unroll 4
        for (int k = 0; k < 512; ++k) {
            float w = bf2f(wc1t[k * H_ + o]);
#pragma unroll
            for (int r = 0; r < 4; ++r) acc[r] += emb[r][k] * w;
        }
#pragma unroll
        for (int r = 0; r < 4; ++r) {
            float pre = acc[r];
            hid[r][o] = pre >= 0.f ? pre : 0.1f * pre;
        }
    }
    __syncthreads();

    {
        int grp = tid >> 5, lane = tid & 31;
        int r = grp >> 1, cc = grp & 1;
        float s = 0.f;
        for (int k = lane; k < H_; k += 32) s += hid[r][k] * wc2[cc * H_ + k];
#pragma unroll
        for (int msk = 16; msk >= 1; msk >>= 1) s += __shfl_xor(s, msk, 32);
        if (lane == 0) out[(size_t)(r0 + r) * 2 + cc] = s + bc2[cc];
    }
}

// ---------------------------------------------------------------------------
extern "C" void kernel_launch(void* const* d_in, const int* in_sizes, int n_in,
                              void* d_out, int out_size, void* d_ws, size_t ws_size,
                              hipStream_t stream)
{
    const float* x      = (const float*)d_in[0];
    const float* w_ih1  = (const float*)d_in[1];
    const float* w_hh1  = (const float*)d_in[2];
    const float* b_ih1  = (const float*)d_in[3];
    const float* b_hh1  = (const float*)d_in[4];
    const float* w_ih2f = (const float*)d_in[5];
    const float* b_ih2f = (const float*)d_in[7];
    const float* b_hh2f = (const float*)d_in[8];
    const float* w_ih2b = (const float*)d_in[9];
    const float* b_ih2b = (const float*)d_in[11];
    const float* b_hh2b = (const float*)d_in[12];
    const float* wc1    = (const float*)d_in[13];
    const float* bc1    = (const float*)d_in[14];
    const float* wc2    = (const float*)d_in[15];
    const float* bc2    = (const float*)d_in[16];
    float* out = (float*)d_out;

    char* p = (char*)d_ws;
    u16* xg   = (u16*)p;  p += (size_t)M_ * G_ * 2;          // 48 MB, [t][n][G]
    u16* xb   = (u16*)p;  p += (size_t)M_ * KP_ * 2;         // 20 MB
    u16* wihb = (u16*)p;  p += (size_t)G_ * KP_ * 2;         // 480 KB
    u16* whpk = (u16*)p;  p += (size_t)48 * 8 * 64 * 8 * 2;  // 384 KB
    u16* w2ft = (u16*)p;  p += (size_t)G_ * H_ * 2;
    u16* w2bt = (u16*)p;  p += (size_t)G_ * H_ * 2;
    u16* wc1t = (u16*)p;  p += (size_t)512 * 256 * 2;
    float* mid = (float*)p; p += (size_t)NROW * H_ * 4;
    float* biasc = (float*)p; p += (size_t)G_ * 4;

    kx_cast<<<M_ * 40 / 256, 256, 0, stream>>>(x, xb);
    k0_prep<<<dim3(960, 5), 256, 0, stream>>>(w_ih1, w_hh1, b_ih1, b_hh1,
                                              w_ih2f, w_ih2b, wc1,
                                              wihb, whpk, w2ft, w2bt, wc1t, biasc);
    k1_xgemm<<<dim3(M_ / 128, G_ / 128), 256, 0, stream>>>(xb, wihb, biasc, xg);
    const int k2_lds = (48 * 2 * 64 * 8 + 16 * 264) * 2;   // 106752 B
    k2_gru<<<32, 512, k2_lds, stream>>>(xg, whpk, b_hh1, mid);
    k3_head<<<128, 256, 0, stream>>>(mid, w2ft, w2bt, b_ih2f, b_hh2f,
                                     b_ih2b, b_hh2b, wc1t, bc1, wc2, bc2, out);
}

// Round 7
// 254.955 us; speedup vs baseline: 3.8821x; 1.0581x over previous
//
#include <hip/hip_runtime.h>
#include <hip/hip_bf16.h>

typedef unsigned short u16;
typedef unsigned int u32;
using short8 = __attribute__((ext_vector_type(8))) short;
using f32x4  = __attribute__((ext_vector_type(4))) float;

#define T_   64
#define D_   300
#define H_   256
#define G_   768            // 3H
#define NROW 512            // useful sequences (s==2)
#define M_   (NROW * T_)    // 32768
#define KP_  320            // K=300 padded to 320 for MFMA

__device__ __forceinline__ float bf2f(u16 v) {
    union { u32 u; float f; } x; x.u = ((u32)v) << 16; return x.f;
}
__device__ __forceinline__ float bf2f_lo(u32 w) {
    union { u32 u; float f; } x; x.u = w << 16; return x.f;
}
__device__ __forceinline__ float bf2f_hi(u32 w) {
    union { u32 u; float f; } x; x.u = w & 0xFFFF0000u; return x.f;
}
__device__ __forceinline__ u16 f2bf(float f) {
    union { u32 u; float f; } x; x.f = f;
    u32 u = x.u;
    u32 r = (u + 0x7FFFu + ((u >> 16) & 1u)) >> 16;   // RNE
    return (u16)r;
}
__device__ __forceinline__ float frcp(float x) {
    float r; asm("v_rcp_f32 %0, %1" : "=v"(r) : "v"(x)); return r;
}
__device__ __forceinline__ float fsigm(float x) { return frcp(1.f + __expf(-x)); }
__device__ __forceinline__ float ftanh(float x) {
    return 1.f - 2.f * frcp(1.f + __expf(2.f * x));
}
__device__ __forceinline__ float sigm(float x) { return 1.f / (1.f + expf(-x)); }

// ---------------------------------------------------------------------------
// KX: cast x[:,2] (f32) -> xb [32768][320] bf16, zero-padded k>=300.
// ---------------------------------------------------------------------------
__global__ __launch_bounds__(256) void kx_cast(
    const float* __restrict__ x, u16* __restrict__ xb)
{
    const int gid = blockIdx.x * 256 + threadIdx.x;   // 32768*40 threads
    const int row = gid / 40, seg = gid - row * 40;
    const int k0 = seg * 8;
    const int n = row >> 6, t = row & 63;
    const float* src = x + (size_t)(n * 256 + 128 + t) * D_;
    union { u16 h[8]; uint4 q; } u;
    if (k0 + 8 <= D_) {
        const float4 a = *reinterpret_cast<const float4*>(src + k0);
        const float4 b = *reinterpret_cast<const float4*>(src + k0 + 4);
        u.h[0] = f2bf(a.x); u.h[1] = f2bf(a.y); u.h[2] = f2bf(a.z); u.h[3] = f2bf(a.w);
        u.h[4] = f2bf(b.x); u.h[5] = f2bf(b.y); u.h[6] = f2bf(b.z); u.h[7] = f2bf(b.w);
    } else {
#pragma unroll
        for (int e = 0; e < 8; ++e)
            u.h[e] = (k0 + e < D_) ? f2bf(src[k0 + e]) : (u16)0;
    }
    *reinterpret_cast<uint4*>(&xb[(size_t)row * KP_ + k0]) = u.q;
}

// ---------------------------------------------------------------------------
// K0: weight prep + combined bias (b_ih1 + b_hh1 for r,z; b_ih1 for n).
// ---------------------------------------------------------------------------
__global__ __launch_bounds__(256) void k0_prep(
    const float* __restrict__ w_ih1, const float* __restrict__ w_hh1,
    const float* __restrict__ b_ih1, const float* __restrict__ b_hh1,
    const float* __restrict__ w2f, const float* __restrict__ w2b,
    const float* __restrict__ wc1,
    u16* __restrict__ wihb, u16* __restrict__ whpk,
    u16* __restrict__ w2ft, u16* __restrict__ w2bt, u16* __restrict__ wc1t,
    float* __restrict__ biasc)
{
    int y = blockIdx.y;
    int tid = blockIdx.x * 256 + threadIdx.x;
    if (y == 0) {
        if (tid < G_ * KP_) {
            int g = tid / KP_, k = tid % KP_;
            wihb[tid] = (k < D_) ? f2bf(w_ih1[g * D_ + k]) : (u16)0;
        }
    } else if (y == 1) {
        if (tid < 48 * 8 * 64) {
            int lane = tid & 63;
            int ks = (tid >> 6) & 7;
            int nt = tid >> 9;
            int g  = nt * 16 + (lane & 15);
            int kb = ks * 32 + ((lane >> 4) << 3);
            union { u16 h[8]; uint4 q; } u;
#pragma unroll
            for (int e = 0; e < 8; ++e) u.h[e] = f2bf(w_hh1[g * H_ + kb + e]);
            *reinterpret_cast<uint4*>(&whpk[(size_t)tid * 8]) = u.q;
        }
    } else if (y == 2 || y == 3) {
        if (tid < G_ * H_) {
            int k = tid / G_, g = tid % G_;
            const float* src = (y == 2) ? w2f : w2b;
            u16* dst = (y == 2) ? w2ft : w2bt;
            dst[tid] = f2bf(src[g * H_ + k]);
        }
    } else {
        if (tid < 512 * 256) {
            int k = tid / 256, o = tid % 256;
            wc1t[tid] = f2bf(wc1[o * 512 + k]);
        }
        if (tid < G_)
            biasc[tid] = b_ih1[tid] + (tid < 2 * H_ ? b_hh1[tid] : 0.f);
    }
}

// ---------------------------------------------------------------------------
// K1: xgp = (xb @ wihb^T + biasc), bf16 MFMA, 128x128 tile.
// Output layout (packed for k2): xgp[((t*512+n)*128 + wv*16 + c)*6 + a*3 + g]
// where unit = wv*32 + a*16 + c, gate g in {r,z,n}.
// ---------------------------------------------------------------------------
__global__ __launch_bounds__(256) void k1_xgemm(
    const u16* __restrict__ xb, const u16* __restrict__ wihb,
    const float* __restrict__ biasc, u16* __restrict__ xgp)
{
    __shared__ alignas(16) u16 As[128 * 40];
    __shared__ alignas(16) u16 Bs[128 * 40];
    const int tid = threadIdx.x;
    const int l = tid & 63, wv = tid >> 6;
    const int wrow = wv >> 1, wcol = wv & 1;
    const int row0 = blockIdx.x * 128, col0 = blockIdx.y * 128;

    f32x4 acc[4][4];
#pragma unroll
    for (int i = 0; i < 4; ++i)
#pragma unroll
        for (int j = 0; j < 4; ++j) acc[i][j] = (f32x4){0.f, 0.f, 0.f, 0.f};

    const int ar = tid >> 1, ah = tid & 1;
    const u16* xrow  = xb + (size_t)(row0 + ar) * KP_;
    const u16* wrowp = wihb + (size_t)(col0 + ar) * KP_;

    for (int k0 = 0; k0 < KP_; k0 += 32) {
        *reinterpret_cast<uint4*>(&As[ar * 40 + ah * 16]) =
            *reinterpret_cast<const uint4*>(xrow + k0 + ah * 16);
        *reinterpret_cast<uint4*>(&As[ar * 40 + ah * 16 + 8]) =
            *reinterpret_cast<const uint4*>(xrow + k0 + ah * 16 + 8);
        *reinterpret_cast<uint4*>(&Bs[ar * 40 + ah * 16]) =
            *reinterpret_cast<const uint4*>(wrowp + k0 + ah * 16);
        *reinterpret_cast<uint4*>(&Bs[ar * 40 + ah * 16 + 8]) =
            *reinterpret_cast<const uint4*>(wrowp + k0 + ah * 16 + 8);
        __syncthreads();

        short8 af[4], bf[4];
#pragma unroll
        for (int fi = 0; fi < 4; ++fi)
            af[fi] = *reinterpret_cast<const short8*>(
                &As[(wrow * 64 + fi * 16 + (l & 15)) * 40 + ((l >> 4) << 3)]);
#pragma unroll
        for (int fj = 0; fj < 4; ++fj)
            bf[fj] = *reinterpret_cast<const short8*>(
                &Bs[(wcol * 64 + fj * 16 + (l & 15)) * 40 + ((l >> 4) << 3)]);
#pragma unroll
        for (int fi = 0; fi < 4; ++fi)
#pragma unroll
            for (int fj = 0; fj < 4; ++fj)
                acc[fi][fj] = __builtin_amdgcn_mfma_f32_16x16x32_bf16(
                    af[fi], bf[fj], acc[fi][fj], 0, 0, 0);
        __syncthreads();
    }

    float bias[4];
#pragma unroll
    for (int fj = 0; fj < 4; ++fj)
        bias[fj] = biasc[col0 + wcol * 64 + fj * 16 + (l & 15)];
#pragma unroll
    for (int fi = 0; fi < 4; ++fi)
#pragma unroll
        for (int fj = 0; fj < 4; ++fj) {
            const int cg = col0 + wcol * 64 + fj * 16 + (l & 15); // 0..767
            const int gate = cg >> 8, unit = cg & 255;
            const int wv8 = unit >> 5, a = (unit >> 4) & 1, c = unit & 15;
#pragma unroll
            for (int q = 0; q < 4; ++q) {
                const int row = row0 + wrow * 64 + fi * 16 + ((l >> 4) << 2) + q;
                const int t = row & 63, n = row >> 6;
                const size_t idx =
                    (((size_t)t * NROW + n) * 128 + wv8 * 16 + c) * 6 + a * 3 + gate;
                xgp[idx] = f2bf(acc[fi][fj][q] + bias[fj]);
            }
        }
}

// ---------------------------------------------------------------------------
// K2 v5: 32 blocks x 512 thr (8 waves, 2/EU -> 256 unified regs).
// Weights ks0-5 in AGPRs (one-time "+a" asm pin: asm-defined => no remat,
// MFMA reads B straight from AGPR). ks6-7 in LDS. hb ping-pong -> ONE
// barrier/step. xgp packed -> 12 coalesced dword loads/step.
// ---------------------------------------------------------------------------
__global__ __launch_bounds__(512)
__attribute__((amdgpu_waves_per_eu(2, 2)))
void k2_gru(const u16* __restrict__ xgp, const u16* __restrict__ whpk,
            const float* __restrict__ b_hh, float* __restrict__ mid)
{
    extern __shared__ u16 smem[];
    u16* wl = smem;                        // ks6-7: 48*2*64*8 u16 = 98304 B
    u16* hb = smem + 48 * 2 * 64 * 8;      // ping-pong 2 x 16*264 u16
    const int tid = threadIdx.x;
    const int l = tid & 63, wv = tid >> 6;   // wv in [0,8)
    const int n0 = blockIdx.x * 16;
    const int col = l & 15, rgrp = l >> 4;
    const int arow = col, klo = rgrp << 3;

    // weights ks 0..5 (36 x short8 = 144 regs), destined for AGPRs
    short8 wr[6][6];
#pragma unroll
    for (int gt = 0; gt < 3; ++gt)
#pragma unroll
        for (int a = 0; a < 2; ++a) {
            const int nt = gt * 16 + wv * 2 + a;
#pragma unroll
            for (int ks = 0; ks < 6; ++ks)
                wr[gt * 2 + a][ks] = *reinterpret_cast<const short8*>(
                    &whpk[(size_t)((nt * 8 + ks) * 64 + l) * 8]);
        }
    // one-time AGPR pin: values become asm-defined (remat illegal), class 'a'
    asm volatile("" :
        "+a"(wr[0][0]),"+a"(wr[0][1]),"+a"(wr[0][2]),"+a"(wr[0][3]),"+a"(wr[0][4]),"+a"(wr[0][5]),
        "+a"(wr[1][0]),"+a"(wr[1][1]),"+a"(wr[1][2]),"+a"(wr[1][3]),"+a"(wr[1][4]),"+a"(wr[1][5]),
        "+a"(wr[2][0]),"+a"(wr[2][1]),"+a"(wr[2][2]),"+a"(wr[2][3]),"+a"(wr[2][4]),"+a"(wr[2][5]));
    asm volatile("" :
        "+a"(wr[3][0]),"+a"(wr[3][1]),"+a"(wr[3][2]),"+a"(wr[3][3]),"+a"(wr[3][4]),"+a"(wr[3][5]),
        "+a"(wr[4][0]),"+a"(wr[4][1]),"+a"(wr[4][2]),"+a"(wr[4][3]),"+a"(wr[4][4]),"+a"(wr[4][5]),
        "+a"(wr[5][0]),"+a"(wr[5][1]),"+a"(wr[5][2]),"+a"(wr[5][3]),"+a"(wr[5][4]),"+a"(wr[5][5]));

    // stage ks 6..7 into LDS
    for (int c = tid; c < 48 * 2 * 64; c += 512) {
        const int nt = c >> 7, j = (c >> 6) & 1, ll = c & 63;
        *reinterpret_cast<uint4*>(&wl[(size_t)c * 8]) =
            *reinterpret_cast<const uint4*>(
                &whpk[(size_t)((nt * 8 + 6 + j) * 64 + ll) * 8]);
    }
    for (int i = tid; i < 2 * 16 * 264 / 2; i += 512) ((u32*)hb)[i] = 0;

    float bhn[2];
    u32 xo[4];
#pragma unroll
    for (int a = 0; a < 2; ++a)
        bhn[a] = b_hh[512 + wv * 32 + a * 16 + col];
#pragma unroll
    for (int q = 0; q < 4; ++q)
        xo[q] = ((u32)(n0 + rgrp * 4 + q) * 128 + wv * 16 + col) * 6;
    float h[2][4] = {};

    __syncthreads();

    int p = 0;
    for (int t = 0; t < T_; ++t) {
        // coalesced packed gate loads: 3 dwords x 4 rows
        u32 pw0[4], pw1[4], pw2[4];
        const u16* xt = xgp + (size_t)t * ((size_t)NROW * 128 * 6);
#pragma unroll
        for (int q = 0; q < 4; ++q) {
            const u32* pp = reinterpret_cast<const u32*>(xt + xo[q]);
            pw0[q] = pp[0]; pw1[q] = pp[1]; pw2[q] = pp[2];
        }

        // MFMA phase: read hb[p]
        const u16* hbr = hb + p * (16 * 264);
        f32x4 acc[6];
#pragma unroll
        for (int m = 0; m < 6; ++m) acc[m] = (f32x4){0.f, 0.f, 0.f, 0.f};
        __builtin_amdgcn_s_setprio(1);
#pragma unroll
        for (int ks = 0; ks < 6; ++ks) {
            const short8 afr = *reinterpret_cast<const short8*>(
                &hbr[arow * 264 + ks * 32 + klo]);
#pragma unroll
            for (int m = 0; m < 6; ++m)
                acc[m] = __builtin_amdgcn_mfma_f32_16x16x32_bf16(
                    afr, wr[m][ks], acc[m], 0, 0, 0);
        }
#pragma unroll
        for (int ks = 6; ks < 8; ++ks) {
            const short8 afr = *reinterpret_cast<const short8*>(
                &hbr[arow * 264 + ks * 32 + klo]);
#pragma unroll
            for (int gt = 0; gt < 3; ++gt)
#pragma unroll
                for (int a = 0; a < 2; ++a) {
                    const int nt2 = (gt * 16 + wv * 2 + a) * 2 + (ks - 6);
                    const short8 bfr = *reinterpret_cast<const short8*>(
                        &wl[(size_t)(nt2 * 64 + l) * 8]);
                    acc[gt * 2 + a] = __builtin_amdgcn_mfma_f32_16x16x32_bf16(
                        afr, bfr, acc[gt * 2 + a], 0, 0, 0);
                }
        }
        __builtin_amdgcn_s_setprio(0);

        // update phase: write hb[p^1] (no barrier needed before: disjoint buf)
        u16* hbw = hb + (p ^ 1) * (16 * 264);
#pragma unroll
        for (int q = 0; q < 4; ++q) {
            // a=0: r=lo(w0) z=hi(w0) n=lo(w1); a=1: r=hi(w1) z=lo(w2) n=hi(w2)
            {
                const float rg = fsigm(bf2f_lo(pw0[q]) + acc[0][q]);
                const float zg = fsigm(bf2f_hi(pw0[q]) + acc[2][q]);
                const float ng = ftanh(bf2f_lo(pw1[q]) + rg * (acc[4][q] + bhn[0]));
                h[0][q] = zg * (h[0][q] - ng) + ng;
                hbw[(rgrp * 4 + q) * 264 + wv * 32 + col] = f2bf(h[0][q]);
            }
            {
                const float rg = fsigm(bf2f_hi(pw1[q]) + acc[1][q]);
                const float zg = fsigm(bf2f_lo(pw2[q]) + acc[3][q]);
                const float ng = ftanh(bf2f_hi(pw2[q]) + rg * (acc[5][q] + bhn[1]));
                h[1][q] = zg * (h[1][q] - ng) + ng;
                hbw[(rgrp * 4 + q) * 264 + wv * 32 + 16 + col] = f2bf(h[1][q]);
            }
        }

        // single barrier per step: writes to p^1 visible before t+1 reads
        asm volatile("s_waitcnt lgkmcnt(0)" ::: "memory");
        __builtin_amdgcn_sched_barrier(0);
        __builtin_amdgcn_s_barrier();
        __builtin_amdgcn_sched_barrier(0);
        p ^= 1;
    }

#pragma unroll
    for (int a = 0; a < 2; ++a)
#pragma unroll
        for (int q = 0; q < 4; ++q)
            mid[(size_t)(n0 + rgrp * 4 + q) * H_ + wv * 32 + a * 16 + col] = h[a][q];
}

// ---------------------------------------------------------------------------
// K3: head. (unchanged)
// ---------------------------------------------------------------------------
__global__ __launch_bounds__(256) void k3_head(
    const float* __restrict__ mid,
    const u16* __restrict__ w2ft, const u16* __restrict__ w2bt,
    const float* __restrict__ b_ih2f, const float* __restrict__ b_hh2f,
    const float* __restrict__ b_ih2b, const float* __restrict__ b_hh2b,
    const u16* __restrict__ wc1t, const float* __restrict__ bc1,
    const float* __restrict__ wc2, const float* __restrict__ bc2,
    float* __restrict__ out)
{
    __shared__ float m[4][H_];
    __shared__ float xg2[2][4][G_];
    __shared__ float emb[4][512];
    __shared__ float hid[4][H_];
    int tid = threadIdx.x;
    int r0 = blockIdx.x * 4;

    for (int i = tid; i < 4 * H_; i += 256) {
        int r = i >> 8, k = i & 255;
        m[r][k] = mid[(size_t)(r0 + r) * H_ + k];
    }
    __syncthreads();

    const int g0 = tid, g1 = tid + 256, g2 = tid + 512;
    float bf0 = b_ih2f[g0] + b_hh2f[g0];
    float bf1 = b_ih2f[g1] + b_hh2f[g1];
    float bf2v = b_ih2f[g2];
    float bb0 = b_ih2b[g0] + b_hh2b[g0];
    float bb1 = b_ih2b[g1] + b_hh2b[g1];
    float bb2v = b_ih2b[g2];
    float af[4][3], ab[4][3];
#pragma unroll
    for (int r = 0; r < 4; ++r) {
        af[r][0] = bf0; af[r][1] = bf1; af[r][2] = bf2v;
        ab[r][0] = bb0; ab[r][1] = bb1; ab[r][2] = bb2v;
    }
#pragma unroll 4
    for (int k = 0; k < H_; ++k) {
        float wf0 = bf2f(w2ft[k * G_ + g0]);
        float wf1 = bf2f(w2ft[k * G_ + g1]);
        float wf2 = bf2f(w2ft[k * G_ + g2]);
        float wb0 = bf2f(w2bt[k * G_ + g0]);
        float wb1 = bf2f(w2bt[k * G_ + g1]);
        float wb2 = bf2f(w2bt[k * G_ + g2]);
#pragma unroll
        for (int r = 0; r < 4; ++r) {
            float mm = m[r][k];
            af[r][0] += mm * wf0; af[r][1] += mm * wf1; af[r][2] += mm * wf2;
            ab[r][0] += mm * wb0; ab[r][1] += mm * wb1; ab[r][2] += mm * wb2;
        }
    }
#pragma unroll
    for (int r = 0; r < 4; ++r) {
        xg2[0][r][g0] = af[r][0]; xg2[0][r][g1] = af[r][1]; xg2[0][r][g2] = af[r][2];
        xg2[1][r][g0] = ab[r][0]; xg2[1][r][g1] = ab[r][1]; xg2[1][r][g2] = ab[r][2];
    }
    __syncthreads();

    {
        const int j = tid;
        float bnf = b_hh2f[512 + j], bnb = b_hh2b[512 + j];
#pragma unroll
        for (int r = 0; r < 4; ++r) {
            float rg = sigm(xg2[0][r][j]);
            float zg = sigm(xg2[0][r][256 + j]);
            float ng = tanhf(xg2[0][r][512 + j] + rg * bnf);
            emb[r][j] = (1.f - zg) * ng;
            rg = sigm(xg2[1][r][j]);
            zg = sigm(xg2[1][r][256 + j]);
            ng = tanhf(xg2[1][r][512 + j] + rg * bnb);
            emb[r][256 + j] = (1.f - zg) * ng;
        }
    }
    __syncthreads();

    {
        const int o = tid;
        float acc[4];
        float b = bc1[o];
#pragma unroll
        for (int r = 0; r < 4; ++r) acc[r] = b;
#pragma unroll 4
        for (int k = 0; k < 512; ++k) {
            float w = bf2f(wc1t[k * H_ + o]);
#pragma unroll
            for (int r = 0; r < 4; ++r) acc[r] += emb[r][k] * w;
        }
#pragma unroll
        for (int r = 0; r < 4; ++r) {
            float pre = acc[r];
            hid[r][o] = pre >= 0.f ? pre : 0.1f * pre;
        }
    }
    __syncthreads();

    {
        int grp = tid >> 5, lane = tid & 31;
        int r = grp >> 1, cc = grp & 1;
        float s = 0.f;
        for (int k = lane; k < H_; k += 32) s += hid[r][k] * wc2[cc * H_ + k];
#pragma unroll
        for (int msk = 16; msk >= 1; msk >>= 1) s += __shfl_xor(s, msk, 32);
        if (lane == 0) out[(size_t)(r0 + r) * 2 + cc] = s + bc2[cc];
    }
}

// ---------------------------------------------------------------------------
extern "C" void kernel_launch(void* const* d_in, const int* in_sizes, int n_in,
                              void* d_out, int out_size, void* d_ws, size_t ws_size,
                              hipStream_t stream)
{
    const float* x      = (const float*)d_in[0];
    const float* w_ih1  = (const float*)d_in[1];
    const float* w_hh1  = (const float*)d_in[2];
    const float* b_ih1  = (const float*)d_in[3];
    const float* b_hh1  = (const float*)d_in[4];
    const float* w_ih2f = (const float*)d_in[5];
    const float* b_ih2f = (const float*)d_in[7];
    const float* b_hh2f = (const float*)d_in[8];
    const float* w_ih2b = (const float*)d_in[9];
    const float* b_ih2b = (const float*)d_in[11];
    const float* b_hh2b = (const float*)d_in[12];
    const float* wc1    = (const float*)d_in[13];
    const float* bc1    = (const float*)d_in[14];
    const float* wc2    = (const float*)d_in[15];
    const float* bc2    = (const float*)d_in[16];
    float* out = (float*)d_out;

    char* p = (char*)d_ws;
    u16* xgp  = (u16*)p;  p += (size_t)M_ * 768 * 2;         // 48 MB packed [t][n][128][6]
    u16* xb   = (u16*)p;  p += (size_t)M_ * KP_ * 2;         // 20 MB
    u16* wihb = (u16*)p;  p += (size_t)G_ * KP_ * 2;         // 480 KB
    u16* whpk = (u16*)p;  p += (size_t)48 * 8 * 64 * 8 * 2;  // 384 KB
    u16* w2ft = (u16*)p;  p += (size_t)G_ * H_ * 2;
    u16* w2bt = (u16*)p;  p += (size_t)G_ * H_ * 2;
    u16* wc1t = (u16*)p;  p += (size_t)512 * 256 * 2;
    float* mid = (float*)p; p += (size_t)NROW * H_ * 4;
    float* biasc = (float*)p; p += (size_t)G_ * 4;

    kx_cast<<<M_ * 40 / 256, 256, 0, stream>>>(x, xb);
    k0_prep<<<dim3(960, 5), 256, 0, stream>>>(w_ih1, w_hh1, b_ih1, b_hh1,
                                              w_ih2f, w_ih2b, wc1,
                                              wihb, whpk, w2ft, w2bt, wc1t, biasc);
    k1_xgemm<<<dim3(M_ / 128, G_ / 128), 256, 0, stream>>>(xb, wihb, biasc, xgp);
    const int k2_lds = (48 * 2 * 64 * 8 + 2 * 16 * 264) * 2;   // 115200 B
    k2_gru<<<32, 512, k2_lds, stream>>>(xgp, whpk, b_hh1, mid);
    k3_head<<<128, 256, 0, stream>>>(mid, w2ft, w2bt, b_ih2f, b_hh2f,
                                     b_ih2b, b_hh2b, wc1t, bc1, wc2, bc2, out);
}

// Round 8
// 233.715 us; speedup vs baseline: 4.2349x; 1.0909x over previous
//
#include <hip/hip_runtime.h>
#include <hip/hip_bf16.h>

typedef unsigned short u16;
typedef unsigned int u32;
using short8 = __attribute__((ext_vector_type(8))) short;
using f32x4  = __attribute__((ext_vector_type(4))) float;

#define T_   64
#define D_   300
#define H_   256
#define G_   768            // 3H
#define NROW 512            // useful sequences (s==2)
#define M_   (NROW * T_)    // 32768
#define KP_  320            // K=300 padded to 320 for MFMA

__device__ __forceinline__ float bf2f(u16 v) {
    union { u32 u; float f; } x; x.u = ((u32)v) << 16; return x.f;
}
__device__ __forceinline__ float bf2f_lo(u32 w) {
    union { u32 u; float f; } x; x.u = w << 16; return x.f;
}
__device__ __forceinline__ float bf2f_hi(u32 w) {
    union { u32 u; float f; } x; x.u = w & 0xFFFF0000u; return x.f;
}
__device__ __forceinline__ u16 f2bf(float f) {
    union { u32 u; float f; } x; x.f = f;
    u32 u = x.u;
    u32 r = (u + 0x7FFFu + ((u >> 16) & 1u)) >> 16;   // RNE
    return (u16)r;
}
__device__ __forceinline__ float frcp(float x) {
    float r; asm("v_rcp_f32 %0, %1" : "=v"(r) : "v"(x)); return r;
}
__device__ __forceinline__ float fsigm(float x) { return frcp(1.f + __expf(-x)); }
__device__ __forceinline__ float ftanh(float x) {
    return 1.f - 2.f * frcp(1.f + __expf(2.f * x));
}
__device__ __forceinline__ float sigm(float x) { return 1.f / (1.f + expf(-x)); }

// ---------------------------------------------------------------------------
// KX: cast x[:,2] (f32) -> xb [32768][320] bf16, zero-padded k>=300.
// ---------------------------------------------------------------------------
__global__ __launch_bounds__(256) void kx_cast(
    const float* __restrict__ x, u16* __restrict__ xb)
{
    const int gid = blockIdx.x * 256 + threadIdx.x;   // 32768*40 threads
    const int row = gid / 40, seg = gid - row * 40;
    const int k0 = seg * 8;
    const int n = row >> 6, t = row & 63;
    const float* src = x + (size_t)(n * 256 + 128 + t) * D_;
    union { u16 h[8]; uint4 q; } u;
    if (k0 + 8 <= D_) {
        const float4 a = *reinterpret_cast<const float4*>(src + k0);
        const float4 b = *reinterpret_cast<const float4*>(src + k0 + 4);
        u.h[0] = f2bf(a.x); u.h[1] = f2bf(a.y); u.h[2] = f2bf(a.z); u.h[3] = f2bf(a.w);
        u.h[4] = f2bf(b.x); u.h[5] = f2bf(b.y); u.h[6] = f2bf(b.z); u.h[7] = f2bf(b.w);
    } else {
#pragma unroll
        for (int e = 0; e < 8; ++e)
            u.h[e] = (k0 + e < D_) ? f2bf(src[k0 + e]) : (u16)0;
    }
    *reinterpret_cast<uint4*>(&xb[(size_t)row * KP_ + k0]) = u.q;
}

// ---------------------------------------------------------------------------
// K0: weight prep + combined bias (b_ih1 + b_hh1 for r,z; b_ih1 for n).
// ---------------------------------------------------------------------------
__global__ __launch_bounds__(256) void k0_prep(
    const float* __restrict__ w_ih1, const float* __restrict__ w_hh1,
    const float* __restrict__ b_ih1, const float* __restrict__ b_hh1,
    const float* __restrict__ w2f, const float* __restrict__ w2b,
    const float* __restrict__ wc1,
    u16* __restrict__ wihb, u16* __restrict__ whpk,
    u16* __restrict__ w2ft, u16* __restrict__ w2bt, u16* __restrict__ wc1t,
    float* __restrict__ biasc)
{
    int y = blockIdx.y;
    int tid = blockIdx.x * 256 + threadIdx.x;
    if (y == 0) {
        if (tid < G_ * KP_) {
            int g = tid / KP_, k = tid % KP_;
            wihb[tid] = (k < D_) ? f2bf(w_ih1[g * D_ + k]) : (u16)0;
        }
    } else if (y == 1) {
        if (tid < 48 * 8 * 64) {
            int lane = tid & 63;
            int ks = (tid >> 6) & 7;
            int nt = tid >> 9;
            int g  = nt * 16 + (lane & 15);
            int kb = ks * 32 + ((lane >> 4) << 3);
            union { u16 h[8]; uint4 q; } u;
#pragma unroll
            for (int e = 0; e < 8; ++e) u.h[e] = f2bf(w_hh1[g * H_ + kb + e]);
            *reinterpret_cast<uint4*>(&whpk[(size_t)tid * 8]) = u.q;
        }
    } else if (y == 2 || y == 3) {
        if (tid < G_ * H_) {
            int k = tid / G_, g = tid % G_;
            const float* src = (y == 2) ? w2f : w2b;
            u16* dst = (y == 2) ? w2ft : w2bt;
            dst[tid] = f2bf(src[g * H_ + k]);
        }
    } else {
        if (tid < 512 * 256) {
            int k = tid / 256, o = tid % 256;
            wc1t[tid] = f2bf(wc1[o * 512 + k]);
        }
        if (tid < G_)
            biasc[tid] = b_ih1[tid] + (tid < 2 * H_ ? b_hh1[tid] : 0.f);
    }
}

// ---------------------------------------------------------------------------
// K1: xgw = (xb @ wihb^T + biasc), bf16 MFMA, 128x128 tile.
// Output layout [t][n][3 gates][128 words] u32; word g*128+wv8*16+c packs
// bf16 pair (unit wv8*32+c, unit wv8*32+16+c). Coalesced u32 stores.
// ---------------------------------------------------------------------------
__global__ __launch_bounds__(256) void k1_xgemm(
    const u16* __restrict__ xb, const u16* __restrict__ wihb,
    const float* __restrict__ biasc, u32* __restrict__ xgw)
{
    __shared__ alignas(16) u16 As[128 * 40];
    __shared__ alignas(16) u16 Bs[128 * 40];
    const int tid = threadIdx.x;
    const int l = tid & 63, wv = tid >> 6;
    const int wrow = wv >> 1, wcol = wv & 1;
    const int row0 = blockIdx.x * 128, col0 = blockIdx.y * 128;

    f32x4 acc[4][4];
#pragma unroll
    for (int i = 0; i < 4; ++i)
#pragma unroll
        for (int j = 0; j < 4; ++j) acc[i][j] = (f32x4){0.f, 0.f, 0.f, 0.f};

    const int ar = tid >> 1, ah = tid & 1;
    const u16* xrow  = xb + (size_t)(row0 + ar) * KP_;
    const u16* wrowp = wihb + (size_t)(col0 + ar) * KP_;

    for (int k0 = 0; k0 < KP_; k0 += 32) {
        *reinterpret_cast<uint4*>(&As[ar * 40 + ah * 16]) =
            *reinterpret_cast<const uint4*>(xrow + k0 + ah * 16);
        *reinterpret_cast<uint4*>(&As[ar * 40 + ah * 16 + 8]) =
            *reinterpret_cast<const uint4*>(xrow + k0 + ah * 16 + 8);
        *reinterpret_cast<uint4*>(&Bs[ar * 40 + ah * 16]) =
            *reinterpret_cast<const uint4*>(wrowp + k0 + ah * 16);
        *reinterpret_cast<uint4*>(&Bs[ar * 40 + ah * 16 + 8]) =
            *reinterpret_cast<const uint4*>(wrowp + k0 + ah * 16 + 8);
        __syncthreads();

        short8 af[4], bf[4];
#pragma unroll
        for (int fi = 0; fi < 4; ++fi)
            af[fi] = *reinterpret_cast<const short8*>(
                &As[(wrow * 64 + fi * 16 + (l & 15)) * 40 + ((l >> 4) << 3)]);
#pragma unroll
        for (int fj = 0; fj < 4; ++fj)
            bf[fj] = *reinterpret_cast<const short8*>(
                &Bs[(wcol * 64 + fj * 16 + (l & 15)) * 40 + ((l >> 4) << 3)]);
#pragma unroll
        for (int fi = 0; fi < 4; ++fi)
#pragma unroll
            for (int fj = 0; fj < 4; ++fj)
                acc[fi][fj] = __builtin_amdgcn_mfma_f32_16x16x32_bf16(
                    af[fi], bf[fj], acc[fi][fj], 0, 0, 0);
        __syncthreads();
    }

    float bias[4];
#pragma unroll
    for (int fj = 0; fj < 4; ++fj)
        bias[fj] = biasc[col0 + wcol * 64 + fj * 16 + (l & 15)];
#pragma unroll
    for (int fi = 0; fi < 4; ++fi)
#pragma unroll
        for (int fjp = 0; fjp < 2; ++fjp) {
            const int cg0 = col0 + wcol * 64 + fjp * 32;     // a=0,c=0 col
            const int g = cg0 >> 8;
            const int wv8 = (cg0 & 255) >> 5;
            const int word = g * 128 + wv8 * 16 + (l & 15);
#pragma unroll
            for (int q = 0; q < 4; ++q) {
                const int row = row0 + wrow * 64 + fi * 16 + ((l >> 4) << 2) + q;
                const int t = row & 63, n = row >> 6;
                const u32 lo = f2bf(acc[fi][2 * fjp][q] + bias[2 * fjp]);
                const u32 hi = f2bf(acc[fi][2 * fjp + 1][q] + bias[2 * fjp + 1]);
                xgw[((size_t)t * NROW + n) * 384 + word] = lo | (hi << 16);
            }
        }
}

// ---------------------------------------------------------------------------
// K2 v6: 64 blocks x 8 rows, 512 thr (8 waves, 2/EU). Weights ks0-5 AGPR-
// pinned, ks6-7 LDS. Update redistributed: lanes 0-31 handle a=0, lanes
// 32-63 receive a=1 accs via shfl -> trans work per SIMD halves. xg
// prefetched one full step ahead (ping-pong regs). One barrier/step.
// ---------------------------------------------------------------------------
__global__ __launch_bounds__(512)
__attribute__((amdgpu_waves_per_eu(2, 2)))
void k2_gru(const u32* __restrict__ xgw, const u16* __restrict__ whpk,
            const float* __restrict__ b_hh, float* __restrict__ mid)
{
    extern __shared__ u16 smem[];
    u16* wl = smem;                        // ks6-7: 48*2*64*8 u16 = 98304 B
    u16* hb = smem + 48 * 2 * 64 * 8;      // ping-pong 2 x 16*264 u16
    const int tid = threadIdx.x;
    const int l = tid & 63, wv = tid >> 6;   // wv in [0,8)
    const int n0 = blockIdx.x * 8;
    const int c = l & 15, rgrp = l >> 4;
    const int arow = c, klo = rgrp << 3;
    const int aSel = rgrp >> 1;              // 0: lanes 0-31, 1: lanes 32-63
    const int rbase = (rgrp & 1) * 4;        // rows rbase..rbase+3
    const int u = wv * 32 + aSel * 16 + c;   // hidden unit this lane updates

    // weights ks 0..5 (36 x short8 = 144 regs), pinned to AGPRs
    short8 wr[6][6];
#pragma unroll
    for (int gt = 0; gt < 3; ++gt)
#pragma unroll
        for (int a = 0; a < 2; ++a) {
            const int nt = gt * 16 + wv * 2 + a;
#pragma unroll
            for (int ks = 0; ks < 6; ++ks)
                wr[gt * 2 + a][ks] = *reinterpret_cast<const short8*>(
                    &whpk[(size_t)((nt * 8 + ks) * 64 + l) * 8]);
        }
    asm volatile("" :
        "+a"(wr[0][0]),"+a"(wr[0][1]),"+a"(wr[0][2]),"+a"(wr[0][3]),"+a"(wr[0][4]),"+a"(wr[0][5]),
        "+a"(wr[1][0]),"+a"(wr[1][1]),"+a"(wr[1][2]),"+a"(wr[1][3]),"+a"(wr[1][4]),"+a"(wr[1][5]),
        "+a"(wr[2][0]),"+a"(wr[2][1]),"+a"(wr[2][2]),"+a"(wr[2][3]),"+a"(wr[2][4]),"+a"(wr[2][5]));
    asm volatile("" :
        "+a"(wr[3][0]),"+a"(wr[3][1]),"+a"(wr[3][2]),"+a"(wr[3][3]),"+a"(wr[3][4]),"+a"(wr[3][5]),
        "+a"(wr[4][0]),"+a"(wr[4][1]),"+a"(wr[4][2]),"+a"(wr[4][3]),"+a"(wr[4][4]),"+a"(wr[4][5]),
        "+a"(wr[5][0]),"+a"(wr[5][1]),"+a"(wr[5][2]),"+a"(wr[5][3]),"+a"(wr[5][4]),"+a"(wr[5][5]));

    // stage ks 6..7 into LDS
    for (int cc = tid; cc < 48 * 2 * 64; cc += 512) {
        const int nt = cc >> 7, j = (cc >> 6) & 1, ll = cc & 63;
        *reinterpret_cast<uint4*>(&wl[(size_t)cc * 8]) =
            *reinterpret_cast<const uint4*>(
                &whpk[(size_t)((nt * 8 + 6 + j) * 64 + ll) * 8]);
    }
    for (int i = tid; i < 2 * 16 * 264 / 2; i += 512) ((u32*)hb)[i] = 0;

    const float bhn = b_hh[512 + u];
    u32 xo[4];
#pragma unroll
    for (int q = 0; q < 4; ++q)
        xo[q] = (u32)(n0 + rbase + q) * 384 + wv * 16 + c;
    float h[4] = {0.f, 0.f, 0.f, 0.f};
    const u32 stepw = (u32)NROW * 384;

    // prologue: load t=0 gates
    u32 xa[3][4], xn2[3][4];
#pragma unroll
    for (int q = 0; q < 4; ++q) {
        xa[0][q] = xgw[xo[q]];
        xa[1][q] = xgw[xo[q] + 128];
        xa[2][q] = xgw[xo[q] + 256];
    }

    __syncthreads();

    int p = 0;
    for (int t = 0; t < T_; ++t) {
        // prefetch next step's gates (fully hidden under this step)
        const u32 tb = (u32)(t + 1 < T_ ? t + 1 : T_ - 1) * stepw;
#pragma unroll
        for (int q = 0; q < 4; ++q) {
            xn2[0][q] = xgw[tb + xo[q]];
            xn2[1][q] = xgw[tb + xo[q] + 128];
            xn2[2][q] = xgw[tb + xo[q] + 256];
        }

        // MFMA phase: read hb[p]
        const u16* hbr = hb + p * (16 * 264);
        f32x4 acc[6];
#pragma unroll
        for (int m = 0; m < 6; ++m) acc[m] = (f32x4){0.f, 0.f, 0.f, 0.f};
        __builtin_amdgcn_s_setprio(1);
#pragma unroll
        for (int ks = 0; ks < 6; ++ks) {
            const short8 afr = *reinterpret_cast<const short8*>(
                &hbr[arow * 264 + ks * 32 + klo]);
#pragma unroll
            for (int m = 0; m < 6; ++m)
                acc[m] = __builtin_amdgcn_mfma_f32_16x16x32_bf16(
                    afr, wr[m][ks], acc[m], 0, 0, 0);
        }
#pragma unroll
        for (int ks = 6; ks < 8; ++ks) {
            const short8 afr = *reinterpret_cast<const short8*>(
                &hbr[arow * 264 + ks * 32 + klo]);
#pragma unroll
            for (int gt = 0; gt < 3; ++gt)
#pragma unroll
                for (int a = 0; a < 2; ++a) {
                    const int nt2 = (gt * 16 + wv * 2 + a) * 2 + (ks - 6);
                    const short8 bfr = *reinterpret_cast<const short8*>(
                        &wl[(size_t)(nt2 * 64 + l) * 8]);
                    acc[gt * 2 + a] = __builtin_amdgcn_mfma_f32_16x16x32_bf16(
                        afr, bfr, acc[gt * 2 + a], 0, 0, 0);
                }
        }
        __builtin_amdgcn_s_setprio(0);

        // redistribute: lanes>=32 take a=1 accs from lane l-32
        float vr[4], vz[4], vn[4];
#pragma unroll
        for (int q = 0; q < 4; ++q) {
            const float r1 = __shfl(acc[1][q], l & 31);
            const float z1 = __shfl(acc[3][q], l & 31);
            const float n1 = __shfl(acc[5][q], l & 31);
            vr[q] = (l < 32) ? acc[0][q] : r1;
            vz[q] = (l < 32) ? acc[2][q] : z1;
            vn[q] = (l < 32) ? acc[4][q] : n1;
        }

        // update phase: 4 (row,unit) values per lane, all 64 lanes active
        u16* hbw = hb + (p ^ 1) * (16 * 264);
#pragma unroll
        for (int q = 0; q < 4; ++q) {
            const float xr = aSel ? bf2f_hi(xa[0][q]) : bf2f_lo(xa[0][q]);
            const float xz = aSel ? bf2f_hi(xa[1][q]) : bf2f_lo(xa[1][q]);
            const float xn = aSel ? bf2f_hi(xa[2][q]) : bf2f_lo(xa[2][q]);
            const float rg = fsigm(xr + vr[q]);
            const float zg = fsigm(xz + vz[q]);
            const float ng = ftanh(xn + rg * (vn[q] + bhn));
            h[q] = zg * (h[q] - ng) + ng;
            hbw[(rbase + q) * 264 + u] = f2bf(h[q]);
        }

        // roll prefetch regs
#pragma unroll
        for (int g = 0; g < 3; ++g)
#pragma unroll
            for (int q = 0; q < 4; ++q) xa[g][q] = xn2[g][q];

        // single barrier per step
        asm volatile("s_waitcnt lgkmcnt(0)" ::: "memory");
        __builtin_amdgcn_sched_barrier(0);
        __builtin_amdgcn_s_barrier();
        __builtin_amdgcn_sched_barrier(0);
        p ^= 1;
    }

#pragma unroll
    for (int q = 0; q < 4; ++q)
        mid[(size_t)(n0 + rbase + q) * H_ + u] = h[q];
}

// ---------------------------------------------------------------------------
// K3: head. (unchanged)
// ---------------------------------------------------------------------------
__global__ __launch_bounds__(256) void k3_head(
    const float* __restrict__ mid,
    const u16* __restrict__ w2ft, const u16* __restrict__ w2bt,
    const float* __restrict__ b_ih2f, const float* __restrict__ b_hh2f,
    const float* __restrict__ b_ih2b, const float* __restrict__ b_hh2b,
    const u16* __restrict__ wc1t, const float* __restrict__ bc1,
    const float* __restrict__ wc2, const float* __restrict__ bc2,
    float* __restrict__ out)
{
    __shared__ float m[4][H_];
    __shared__ float xg2[2][4][G_];
    __shared__ float emb[4][512];
    __shared__ float hid[4][H_];
    int tid = threadIdx.x;
    int r0 = blockIdx.x * 4;

    for (int i = tid; i < 4 * H_; i += 256) {
        int r = i >> 8, k = i & 255;
        m[r][k] = mid[(size_t)(r0 + r) * H_ + k];
    }
    __syncthreads();

    const int g0 = tid, g1 = tid + 256, g2 = tid + 512;
    float bf0 = b_ih2f[g0] + b_hh2f[g0];
    float bf1 = b_ih2f[g1] + b_hh2f[g1];
    float bf2v = b_ih2f[g2];
    float bb0 = b_ih2b[g0] + b_hh2b[g0];
    float bb1 = b_ih2b[g1] + b_hh2b[g1];
    float bb2v = b_ih2b[g2];
    float af[4][3], ab[4][3];
#pragma unroll
    for (int r = 0; r < 4; ++r) {
        af[r][0] = bf0; af[r][1] = bf1; af[r][2] = bf2v;
        ab[r][0] = bb0; ab[r][1] = bb1; ab[r][2] = bb2v;
    }
#pragma unroll 4
    for (int k = 0; k < H_; ++k) {
        float wf0 = bf2f(w2ft[k * G_ + g0]);
        float wf1 = bf2f(w2ft[k * G_ + g1]);
        float wf2 = bf2f(w2ft[k * G_ + g2]);
        float wb0 = bf2f(w2bt[k * G_ + g0]);
        float wb1 = bf2f(w2bt[k * G_ + g1]);
        float wb2 = bf2f(w2bt[k * G_ + g2]);
#pragma unroll
        for (int r = 0; r < 4; ++r) {
            float mm = m[r][k];
            af[r][0] += mm * wf0; af[r][1] += mm * wf1; af[r][2] += mm * wf2;
            ab[r][0] += mm * wb0; ab[r][1] += mm * wb1; ab[r][2] += mm * wb2;
        }
    }
#pragma unroll
    for (int r = 0; r < 4; ++r) {
        xg2[0][r][g0] = af[r][0]; xg2[0][r][g1] = af[r][1]; xg2[0][r][g2] = af[r][2];
        xg2[1][r][g0] = ab[r][0]; xg2[1][r][g1] = ab[r][1]; xg2[1][r][g2] = ab[r][2];
    }
    __syncthreads();

    {
        const int j = tid;
        float bnf = b_hh2f[512 + j], bnb = b_hh2b[512 + j];
#pragma unroll
        for (int r = 0; r < 4; ++r) {
            float rg = sigm(xg2[0][r][j]);
            float zg = sigm(xg2[0][r][256 + j]);
            float ng = tanhf(xg2[0][r][512 + j] + rg * bnf);
            emb[r][j] = (1.f - zg) * ng;
            rg = sigm(xg2[1][r][j]);
            zg = sigm(xg2[1][r][256 + j]);
            ng = tanhf(xg2[1][r][512 + j] + rg * bnb);
            emb[r][256 + j] = (1.f - zg) * ng;
        }
    }
    __syncthreads();

    {
        const int o = tid;
        float acc[4];
        float b = bc1[o];
#pragma unroll
        for (int r = 0; r < 4; ++r) acc[r] = b;
#pragma unroll 4
        for (int k = 0; k < 512; ++k) {
            float w = bf2f(wc1t[k * H_ + o]);
#pragma unroll
            for (int r = 0; r < 4; ++r) acc[r] += emb[r][k] * w;
        }
#pragma unroll
        for (int r = 0; r < 4; ++r) {
            float pre = acc[r];
            hid[r][o] = pre >= 0.f ? pre : 0.1f * pre;
        }
    }
    __syncthreads();

    {
        int grp = tid >> 5, lane = tid & 31;
        int r = grp >> 1, cc = grp & 1;
        float s = 0.f;
        for (int k = lane; k < H_; k += 32) s += hid[r][k] * wc2[cc * H_ + k];
#pragma unroll
        for (int msk = 16; msk >= 1; msk >>= 1) s += __shfl_xor(s, msk, 32);
        if (lane == 0) out[(size_t)(r0 + r) * 2 + cc] = s + bc2[cc];
    }
}

// ---------------------------------------------------------------------------
extern "C" void kernel_launch(void* const* d_in, const int* in_sizes, int n_in,
                              void* d_out, int out_size, void* d_ws, size_t ws_size,
                              hipStream_t stream)
{
    const float* x      = (const float*)d_in[0];
    const float* w_ih1  = (const float*)d_in[1];
    const float* w_hh1  = (const float*)d_in[2];
    const float* b_ih1  = (const float*)d_in[3];
    const float* b_hh1  = (const float*)d_in[4];
    const float* w_ih2f = (const float*)d_in[5];
    const float* b_ih2f = (const float*)d_in[7];
    const float* b_hh2f = (const float*)d_in[8];
    const float* w_ih2b = (const float*)d_in[9];
    const float* b_ih2b = (const float*)d_in[11];
    const float* b_hh2b = (const float*)d_in[12];
    const float* wc1    = (const float*)d_in[13];
    const float* bc1    = (const float*)d_in[14];
    const float* wc2    = (const float*)d_in[15];
    const float* bc2    = (const float*)d_in[16];
    float* out = (float*)d_out;

    char* p = (char*)d_ws;
    u32* xgw  = (u32*)p;  p += (size_t)M_ * 384 * 4;         // 48 MB [t][n][3][128]u32
    u16* xb   = (u16*)p;  p += (size_t)M_ * KP_ * 2;         // 20 MB
    u16* wihb = (u16*)p;  p += (size_t)G_ * KP_ * 2;         // 480 KB
    u16* whpk = (u16*)p;  p += (size_t)48 * 8 * 64 * 8 * 2;  // 384 KB
    u16* w2ft = (u16*)p;  p += (size_t)G_ * H_ * 2;
    u16* w2bt = (u16*)p;  p += (size_t)G_ * H_ * 2;
    u16* wc1t = (u16*)p;  p += (size_t)512 * 256 * 2;
    float* mid = (float*)p; p += (size_t)NROW * H_ * 4;
    float* biasc = (float*)p; p += (size_t)G_ * 4;

    kx_cast<<<M_ * 40 / 256, 256, 0, stream>>>(x, xb);
    k0_prep<<<dim3(960, 5), 256, 0, stream>>>(w_ih1, w_hh1, b_ih1, b_hh1,
                                              w_ih2f, w_ih2b, wc1,
                                              wihb, whpk, w2ft, w2bt, wc1t, biasc);
    k1_xgemm<<<dim3(M_ / 128, G_ / 128), 256, 0, stream>>>(xb, wihb, biasc, xgw);
    const int k2_lds = (48 * 2 * 64 * 8 + 2 * 16 * 264) * 2;   // 115200 B
    k2_gru<<<64, 512, k2_lds, stream>>>(xgw, whpk, b_hh1, mid);
    k3_head<<<128, 256, 0, stream>>>(mid, w2ft, w2bt, b_ih2f, b_hh2f,
                                     b_ih2b, b_hh2b, wc1t, bc1, wc2, bc2, out);
}